// Round 1
// baseline (9539.954 us; speedup 1.0000x reference)
//
#include <hip/hip_runtime.h>
#include <math.h>

#define NN 100000
#define NE 1600000

// workspace layout (in floats)
#define OFF_X1   ((size_t)0)                       // N*16
#define OFF_SS   ((size_t)NN * 16)                 // N*48
#define OFF_MID  (OFF_SS + (size_t)NN * 48)        // N*64  (zeroed)
#define OFF_MID2 (OFF_MID + (size_t)NN * 64)       // N*48  (zeroed, adjacent to MID)
#define OFF_H0   (OFF_MID2 + (size_t)NN * 48)      // N*32
#define OFF_HV   (OFF_H0 + (size_t)NN * 32)        // N*48
#define OFF_S2   (OFF_HV + (size_t)NN * 48)        // N

#define INV_SQRT10 0.31622776601683794f
#define INV_SQRT32 0.17677669529663687f
#define INV_SQRT48 0.14433756729740643f
#define INV_SQRT3  0.57735026918962576f
#define C_S 0.3826834323650898f
#define C_X 0.9238795325112867f

__device__ __forceinline__ float silu_f(float x) { return x / (1.f + __expf(-x)); }
__device__ __forceinline__ float sigm_f(float x) { return 1.f / (1.f + __expf(-x)); }

// ---------------- kernel 1: node pre  (s_scal, x1) ----------------
__global__ __launch_bounds__(256) void k1_nodes(
    const float* __restrict__ node_input, const float* __restrict__ node_attr,
    const float* __restrict__ W_sc1, const float* __restrict__ W_lin1_1,
    float* __restrict__ x1, float* __restrict__ ssc)
{
    __shared__ float4 sW1[192];  // W_sc1 16x48
    __shared__ float4 sW2[64];   // W_lin1_1 16x16
    for (int i = threadIdx.x; i < 192; i += 256) sW1[i] = ((const float4*)W_sc1)[i];
    if (threadIdx.x < 64) sW2[threadIdx.x] = ((const float4*)W_lin1_1)[threadIdx.x];
    __syncthreads();
    int n = blockIdx.x * 256 + threadIdx.x;
    if (n >= NN) return;

    float ni[16];
    {
        const float4* p = reinterpret_cast<const float4*>(node_input + (size_t)n * 16);
        #pragma unroll
        for (int q = 0; q < 4; ++q) {
            float4 v = p[q];
            ni[q*4+0] = v.x; ni[q*4+1] = v.y; ni[q*4+2] = v.z; ni[q*4+3] = v.w;
        }
    }
    float sc = 0.25f * node_attr[n];

    float4* po = reinterpret_cast<float4*>(ssc + (size_t)n * 48);
    #pragma unroll
    for (int jb = 0; jb < 12; ++jb) {
        float a0 = 0.f, a1 = 0.f, a2 = 0.f, a3 = 0.f;
        #pragma unroll
        for (int u = 0; u < 16; ++u) {
            float x = ni[u]; float4 w = sW1[u * 12 + jb];
            a0 += x * w.x; a1 += x * w.y; a2 += x * w.z; a3 += x * w.w;
        }
        float4 o; o.x = a0 * sc; o.y = a1 * sc; o.z = a2 * sc; o.w = a3 * sc;
        po[jb] = o;
    }
    float4* px = reinterpret_cast<float4*>(x1 + (size_t)n * 16);
    #pragma unroll
    for (int jb = 0; jb < 4; ++jb) {
        float a0 = 0.f, a1 = 0.f, a2 = 0.f, a3 = 0.f;
        #pragma unroll
        for (int u = 0; u < 16; ++u) {
            float x = ni[u]; float4 w = sW2[u * 4 + jb];
            a0 += x * w.x; a1 += x * w.y; a2 += x * w.z; a3 += x * w.w;
        }
        float4 o; o.x = a0 * sc; o.y = a1 * sc; o.z = a2 * sc; o.w = a3 * sc;
        px[jb] = o;
    }
}

// ---------------- kernel 2: edge pass 1 (radial1 + f0/f1 + scatter) ----------------
__global__ __launch_bounds__(256) void k2_edges(
    const float* __restrict__ ele, const float* __restrict__ eattr,
    const float* __restrict__ fc1_W1, const float* __restrict__ fc1_W2,
    const int* __restrict__ esrc, const int* __restrict__ edst,
    const float* __restrict__ x1, float* __restrict__ mid)
{
    __shared__ float4 sW1[160];  // fc1_W1 10x64
    __shared__ float4 sW2[512];  // fc1_W2 64x32
    for (int i = threadIdx.x; i < 160; i += 256) sW1[i] = ((const float4*)fc1_W1)[i];
    for (int i = threadIdx.x; i < 512; i += 256) sW2[i] = ((const float4*)fc1_W2)[i];
    __syncthreads();
    int e = blockIdx.x * 256 + threadIdx.x;
    if (e >= NE) return;

    float el[10];
    #pragma unroll
    for (int k = 0; k < 10; ++k) el[k] = ele[(size_t)e * 10 + k] * INV_SQRT10;

    float h[64];
    #pragma unroll
    for (int jb = 0; jb < 16; ++jb) {
        float a0 = 0.f, a1 = 0.f, a2 = 0.f, a3 = 0.f;
        #pragma unroll
        for (int k = 0; k < 10; ++k) {
            float x = el[k]; float4 w = sW1[k * 16 + jb];
            a0 += x * w.x; a1 += x * w.y; a2 += x * w.z; a3 += x * w.w;
        }
        h[jb*4+0] = silu_f(a0); h[jb*4+1] = silu_f(a1);
        h[jb*4+2] = silu_f(a2); h[jb*4+3] = silu_f(a3);
    }

    int s = esrc[e], d = edst[e];
    float xs[16];
    {
        const float4* p = reinterpret_cast<const float4*>(x1 + (size_t)s * 16);
        #pragma unroll
        for (int q = 0; q < 4; ++q) {
            float4 v = p[q];
            xs[q*4+0] = v.x; xs[q*4+1] = v.y; xs[q*4+2] = v.z; xs[q*4+3] = v.w;
        }
    }
    float4 ea = reinterpret_cast<const float4*>(eattr)[e];
    float* md = mid + (size_t)d * 64;
    const float c = 0.125f * 0.25f;  // radial 1/sqrt(64) * segment 1/sqrt(16)

    #pragma unroll
    for (int jb = 0; jb < 8; ++jb) {
        float a0 = 0.f, a1 = 0.f, a2 = 0.f, a3 = 0.f;
        #pragma unroll
        for (int i = 0; i < 64; ++i) {
            float x = h[i]; float4 w = sW2[i * 8 + jb];
            a0 += x * w.x; a1 += x * w.y; a2 += x * w.z; a3 += x * w.w;
        }
        if (jb < 4) {  // f0 = xs * ea0 * w[:16]
            int j = jb * 4;
            atomicAdd(md + j + 0, xs[j+0] * ea.x * a0 * c);
            atomicAdd(md + j + 1, xs[j+1] * ea.x * a1 * c);
            atomicAdd(md + j + 2, xs[j+2] * ea.x * a2 * c);
            atomicAdd(md + j + 3, xs[j+3] * ea.x * a3 * c);
        } else {       // f1[u][cc] = xs[u]*w[16+u]*ea1[cc]
            int u = (jb - 4) * 4;
            float t0 = xs[u+0] * a0 * c, t1 = xs[u+1] * a1 * c;
            float t2 = xs[u+2] * a2 * c, t3 = xs[u+3] * a3 * c;
            atomicAdd(md + 16 + (u+0)*3 + 0, t0 * ea.y);
            atomicAdd(md + 16 + (u+0)*3 + 1, t0 * ea.z);
            atomicAdd(md + 16 + (u+0)*3 + 2, t0 * ea.w);
            atomicAdd(md + 16 + (u+1)*3 + 0, t1 * ea.y);
            atomicAdd(md + 16 + (u+1)*3 + 1, t1 * ea.z);
            atomicAdd(md + 16 + (u+1)*3 + 2, t1 * ea.w);
            atomicAdd(md + 16 + (u+2)*3 + 0, t2 * ea.y);
            atomicAdd(md + 16 + (u+2)*3 + 1, t2 * ea.z);
            atomicAdd(md + 16 + (u+2)*3 + 2, t2 * ea.w);
            atomicAdd(md + 16 + (u+3)*3 + 0, t3 * ea.y);
            atomicAdd(md + 16 + (u+3)*3 + 1, t3 * ea.z);
            atomicAdd(md + 16 + (u+3)*3 + 2, t3 * ea.w);
        }
    }
}

// ---------------- kernel 3: node mid (gates, h0, hv, s2) ----------------
__global__ __launch_bounds__(256) void k3_nodes(
    const float* __restrict__ node_attr, const float* __restrict__ ssc,
    const float* __restrict__ mid,
    const float* __restrict__ W_l2s, const float* __restrict__ W_l2v,
    const float* __restrict__ W_sc2, const float* __restrict__ W12s,
    const float* __restrict__ W12v,
    float* __restrict__ h0, float* __restrict__ hv, float* __restrict__ s2)
{
    __shared__ float4 sA[192];  // W_l2s_1 16x48
    __shared__ float  sB[256];  // W_l2v_1 16x16
    __shared__ float  sC[32];   // W_sc2 32x1
    __shared__ float4 sD[256];  // W_lin1_2s 32x32
    __shared__ float  sE[256];  // W_lin1_2v 16x16
    for (int i = threadIdx.x; i < 192; i += 256) sA[i] = ((const float4*)W_l2s)[i];
    if (threadIdx.x < 256) sB[threadIdx.x] = W_l2v[threadIdx.x];
    if (threadIdx.x < 32)  sC[threadIdx.x] = W_sc2[threadIdx.x];
    for (int i = threadIdx.x; i < 256; i += 256) sD[i] = ((const float4*)W12s)[i];
    if (threadIdx.x < 256) sE[threadIdx.x] = W12v[threadIdx.x];
    __syncthreads();
    int n = blockIdx.x * 256 + threadIdx.x;
    if (n >= NN) return;

    float na = node_attr[n];
    float m[64];
    {
        const float4* p = reinterpret_cast<const float4*>(mid + (size_t)n * 64);
        #pragma unroll
        for (int q = 0; q < 16; ++q) {
            float4 v = p[q];
            m[q*4+0] = v.x; m[q*4+1] = v.y; m[q*4+2] = v.z; m[q*4+3] = v.w;
        }
    }

    float scal[32], gates[16];
    const float4* pss = reinterpret_cast<const float4*>(ssc + (size_t)n * 48);
    #pragma unroll
    for (int jb = 0; jb < 12; ++jb) {
        float a0 = 0.f, a1 = 0.f, a2 = 0.f, a3 = 0.f;
        #pragma unroll
        for (int u = 0; u < 16; ++u) {
            float x = m[u]; float4 w = sA[u * 12 + jb];
            a0 += x * w.x; a1 += x * w.y; a2 += x * w.z; a3 += x * w.w;
        }
        float4 sv = pss[jb];
        float cc = 0.25f * na;
        float g0 = C_S * sv.x + C_X * a0 * cc;
        float g1 = C_S * sv.y + C_X * a1 * cc;
        float g2 = C_S * sv.z + C_X * a2 * cc;
        float g3 = C_S * sv.w + C_X * a3 * cc;
        if (jb < 8) {
            int j = jb * 4;
            scal[j+0] = silu_f(g0); scal[j+1] = silu_f(g1);
            scal[j+2] = silu_f(g2); scal[j+3] = silu_f(g3);
        } else {
            int j = jb * 4 - 32;
            gates[j+0] = sigm_f(g0); gates[j+1] = sigm_f(g1);
            gates[j+2] = sigm_f(g2); gates[j+3] = sigm_f(g3);
        }
    }

    // vec[w][cc] = (sum_u m1[u][cc] * W_l2v[u][w]) * 0.25 * na * gates[w]
    float vec[48];
    #pragma unroll
    for (int w = 0; w < 16; ++w) {
        float a0 = 0.f, a1 = 0.f, a2 = 0.f;
        #pragma unroll
        for (int u = 0; u < 16; ++u) {
            float wt = sB[u * 16 + w];
            a0 += m[16 + u*3 + 0] * wt;
            a1 += m[16 + u*3 + 1] * wt;
            a2 += m[16 + u*3 + 2] * wt;
        }
        float gt = gates[w] * 0.25f * na;
        vec[w*3+0] = a0 * gt; vec[w*3+1] = a1 * gt; vec[w*3+2] = a2 * gt;
    }

    // s2
    {
        float acc = 0.f;
        #pragma unroll
        for (int j = 0; j < 32; ++j) acc += scal[j] * sC[j];
        s2[n] = acc * INV_SQRT32 * na;
    }

    // h0 = scal @ W_lin1_2s * inv_sqrt32 * na
    {
        float c2 = INV_SQRT32 * na;
        float4* ph = reinterpret_cast<float4*>(h0 + (size_t)n * 32);
        #pragma unroll
        for (int jb = 0; jb < 8; ++jb) {
            float a0 = 0.f, a1 = 0.f, a2 = 0.f, a3 = 0.f;
            #pragma unroll
            for (int i = 0; i < 32; ++i) {
                float x = scal[i]; float4 w = sD[i * 8 + jb];
                a0 += x * w.x; a1 += x * w.y; a2 += x * w.z; a3 += x * w.w;
            }
            float4 o; o.x = a0 * c2; o.y = a1 * c2; o.z = a2 * c2; o.w = a3 * c2;
            ph[jb] = o;
        }
    }

    // hv[w][cc] = (sum_u vec[u][cc]*W_lin1_2v[u][w]) * 0.25 * na
    {
        float c3 = 0.25f * na;
        float hvv[48];
        #pragma unroll
        for (int w = 0; w < 16; ++w) {
            float a0 = 0.f, a1 = 0.f, a2 = 0.f;
            #pragma unroll
            for (int u = 0; u < 16; ++u) {
                float wt = sE[u * 16 + w];
                a0 += vec[u*3+0] * wt; a1 += vec[u*3+1] * wt; a2 += vec[u*3+2] * wt;
            }
            hvv[w*3+0] = a0 * c3; hvv[w*3+1] = a1 * c3; hvv[w*3+2] = a2 * c3;
        }
        float4* ph = reinterpret_cast<float4*>(hv + (size_t)n * 48);
        #pragma unroll
        for (int q = 0; q < 12; ++q) {
            float4 o; o.x = hvv[q*4+0]; o.y = hvv[q*4+1]; o.z = hvv[q*4+2]; o.w = hvv[q*4+3];
            ph[q] = o;
        }
    }
}

// ---------------- kernel 4: edge pass 2 (radial2 + fa/fb + scatter) ----------------
__global__ __launch_bounds__(256) void k4_edges(
    const float* __restrict__ ele, const float* __restrict__ eattr,
    const float* __restrict__ fc2_W1, const float* __restrict__ fc2_W2,
    const int* __restrict__ esrc, const int* __restrict__ edst,
    const float* __restrict__ h0, const float* __restrict__ hv,
    float* __restrict__ mid2)
{
    __shared__ float4 sW1[160];  // fc2_W1 10x64
    __shared__ float4 sW2[768];  // fc2_W2 64x48
    for (int i = threadIdx.x; i < 160; i += 256) sW1[i] = ((const float4*)fc2_W1)[i];
    for (int i = threadIdx.x; i < 768; i += 256) sW2[i] = ((const float4*)fc2_W2)[i];
    __syncthreads();
    int e = blockIdx.x * 256 + threadIdx.x;
    if (e >= NE) return;

    float el[10];
    #pragma unroll
    for (int k = 0; k < 10; ++k) el[k] = ele[(size_t)e * 10 + k] * INV_SQRT10;

    float h[64];
    #pragma unroll
    for (int jb = 0; jb < 16; ++jb) {
        float a0 = 0.f, a1 = 0.f, a2 = 0.f, a3 = 0.f;
        #pragma unroll
        for (int k = 0; k < 10; ++k) {
            float x = el[k]; float4 w = sW1[k * 16 + jb];
            a0 += x * w.x; a1 += x * w.y; a2 += x * w.z; a3 += x * w.w;
        }
        h[jb*4+0] = silu_f(a0); h[jb*4+1] = silu_f(a1);
        h[jb*4+2] = silu_f(a2); h[jb*4+3] = silu_f(a3);
    }

    int s = esrc[e], d = edst[e];
    float4 ea = reinterpret_cast<const float4*>(eattr)[e];

    float g0[32];
    {
        const float4* p = reinterpret_cast<const float4*>(h0 + (size_t)s * 32);
        #pragma unroll
        for (int q = 0; q < 8; ++q) {
            float4 v = p[q];
            g0[q*4+0] = v.x; g0[q*4+1] = v.y; g0[q*4+2] = v.z; g0[q*4+3] = v.w;
        }
    }
    float dv[16];
    {
        float vv[48];
        const float4* p = reinterpret_cast<const float4*>(hv + (size_t)s * 48);
        #pragma unroll
        for (int q = 0; q < 12; ++q) {
            float4 v = p[q];
            vv[q*4+0] = v.x; vv[q*4+1] = v.y; vv[q*4+2] = v.z; vv[q*4+3] = v.w;
        }
        #pragma unroll
        for (int u = 0; u < 16; ++u)
            dv[u] = vv[u*3+0] * ea.y + vv[u*3+1] * ea.z + vv[u*3+2] * ea.w;
    }

    float* md = mid2 + (size_t)d * 48;
    const float c = 0.125f * 0.25f;  // radial 1/8 * segment 1/4
    #pragma unroll
    for (int jb = 0; jb < 12; ++jb) {
        float a0 = 0.f, a1 = 0.f, a2 = 0.f, a3 = 0.f;
        #pragma unroll
        for (int i = 0; i < 64; ++i) {
            float x = h[i]; float4 w = sW2[i * 12 + jb];
            a0 += x * w.x; a1 += x * w.y; a2 += x * w.z; a3 += x * w.w;
        }
        int j = jb * 4;
        if (jb < 8) {  // fa = g0 * ea0 * w2[:32]
            atomicAdd(md + j + 0, g0[j+0] * ea.x * a0 * c);
            atomicAdd(md + j + 1, g0[j+1] * ea.x * a1 * c);
            atomicAdd(md + j + 2, g0[j+2] * ea.x * a2 * c);
            atomicAdd(md + j + 3, g0[j+3] * ea.x * a3 * c);
        } else {       // fb[u] = dv[u] * inv_sqrt3 * w2[32+u]
            int u = j - 32;
            const float c2 = c * INV_SQRT3;
            atomicAdd(md + j + 0, dv[u+0] * a0 * c2);
            atomicAdd(md + j + 1, dv[u+1] * a1 * c2);
            atomicAdd(md + j + 2, dv[u+2] * a2 * c2);
            atomicAdd(md + j + 3, dv[u+3] * a3 * c2);
        }
    }
}

// ---------------- kernel 5: node final ----------------
__global__ __launch_bounds__(256) void k5_nodes(
    const float* __restrict__ node_attr, const float* __restrict__ mid2,
    const float* __restrict__ W_lin2_2, const float* __restrict__ s2,
    float* __restrict__ out)
{
    __shared__ float sw[48];
    if (threadIdx.x < 48) sw[threadIdx.x] = W_lin2_2[threadIdx.x];
    __syncthreads();
    int n = blockIdx.x * 256 + threadIdx.x;
    if (n >= NN) return;
    float acc = 0.f;
    const float4* p = reinterpret_cast<const float4*>(mid2 + (size_t)n * 48);
    #pragma unroll
    for (int q = 0; q < 12; ++q) {
        float4 v = p[q];
        acc += v.x * sw[q*4+0] + v.y * sw[q*4+1] + v.z * sw[q*4+2] + v.w * sw[q*4+3];
    }
    out[n] = C_S * s2[n] + C_X * acc * INV_SQRT48 * node_attr[n];
}

extern "C" void kernel_launch(void* const* d_in, const int* in_sizes, int n_in,
                              void* d_out, int out_size, void* d_ws, size_t ws_size,
                              hipStream_t stream)
{
    const float* node_input = (const float*)d_in[0];
    const float* node_attr  = (const float*)d_in[1];
    const float* edge_attr  = (const float*)d_in[2];
    const float* ele        = (const float*)d_in[3];
    const float* W_sc1      = (const float*)d_in[4];
    const float* W_lin1_1   = (const float*)d_in[5];
    const float* fc1_W1     = (const float*)d_in[6];
    const float* fc1_W2     = (const float*)d_in[7];
    const float* W_l2s_1    = (const float*)d_in[8];
    const float* W_l2v_1    = (const float*)d_in[9];
    const float* W_sc2      = (const float*)d_in[10];
    const float* W_lin1_2s  = (const float*)d_in[11];
    const float* W_lin1_2v  = (const float*)d_in[12];
    const float* fc2_W1     = (const float*)d_in[13];
    const float* fc2_W2     = (const float*)d_in[14];
    const float* W_lin2_2   = (const float*)d_in[15];
    const int*   esrc       = (const int*)d_in[16];
    const int*   edst       = (const int*)d_in[17];
    float* out = (float*)d_out;
    float* ws  = (float*)d_ws;

    float* x1   = ws + OFF_X1;
    float* ssc  = ws + OFF_SS;
    float* mid  = ws + OFF_MID;
    float* mid2 = ws + OFF_MID2;
    float* h0   = ws + OFF_H0;
    float* hv   = ws + OFF_HV;
    float* s2   = ws + OFF_S2;

    // zero the two accumulation buffers (adjacent in ws)
    hipMemsetAsync(mid, 0, (size_t)NN * (64 + 48) * sizeof(float), stream);

    dim3 blk(256);
    int nodeGrid = (NN + 255) / 256;
    int edgeGrid = (NE + 255) / 256;

    k1_nodes<<<nodeGrid, blk, 0, stream>>>(node_input, node_attr, W_sc1, W_lin1_1, x1, ssc);
    k2_edges<<<edgeGrid, blk, 0, stream>>>(ele, edge_attr, fc1_W1, fc1_W2, esrc, edst, x1, mid);
    k3_nodes<<<nodeGrid, blk, 0, stream>>>(node_attr, ssc, mid, W_l2s_1, W_l2v_1, W_sc2,
                                           W_lin1_2s, W_lin1_2v, h0, hv, s2);
    k4_edges<<<edgeGrid, blk, 0, stream>>>(ele, edge_attr, fc2_W1, fc2_W2, esrc, edst,
                                           h0, hv, mid2);
    k5_nodes<<<nodeGrid, blk, 0, stream>>>(node_attr, mid2, W_lin2_2, s2, out);
}

// Round 2
// 6944.014 us; speedup vs baseline: 1.3738x; 1.3738x over previous
//
#include <hip/hip_runtime.h>
#include <math.h>

#define NN 100000
#define NE 1600000

// ---- workspace layout (element offsets; all 4-byte elems) ----
#define OFF_X1   ((size_t)0)                  // N*16 f
#define OFF_SS   ((size_t)NN * 16)            // N*48 f
#define OFF_MID  ((size_t)NN * 64)            // N*64 f
#define OFF_H0   ((size_t)NN * 128)           // N*32 f
#define OFF_HV   ((size_t)NN * 160)           // N*48 f
#define OFF_S2   ((size_t)NN * 208)           // N   f
#define OFF_CNT  ((size_t)NN * 209)           // N   i
#define OFF_OFFS ((size_t)NN * 210)           // N   i
#define OFF_CUR  ((size_t)NN * 211)           // N   i
#define OFF_PART ((size_t)NN * 212)           // 128 i
#define OFF_SORT (OFF_PART + 128)             // E   i

#define INV_SQRT10 0.31622776601683794f
#define INV_SQRT32 0.17677669529663687f
#define INV_SQRT48 0.14433756729740643f
#define INV_SQRT3  0.57735026918962576f
#define C_S 0.3826834323650898f
#define C_X 0.9238795325112867f

#define SCAN_B 1024
#define NSCAN ((NN + SCAN_B - 1) / SCAN_B)    // 98

__device__ __forceinline__ float silu_f(float x) { return x / (1.f + __expf(-x)); }
__device__ __forceinline__ float sigm_f(float x) { return 1.f / (1.f + __expf(-x)); }

// ---------------- CSR build ----------------
__global__ __launch_bounds__(256) void hist_k(const int* __restrict__ edst,
                                              int* __restrict__ cnt)
{
    int e = blockIdx.x * 256 + threadIdx.x;
    if (e >= NE) return;
    atomicAdd(&cnt[edst[e]], 1);
}

__global__ __launch_bounds__(SCAN_B) void s1_partial(const int* __restrict__ cnt,
                                                     int* __restrict__ part)
{
    __shared__ int sm[SCAN_B];
    int i = blockIdx.x * SCAN_B + threadIdx.x;
    sm[threadIdx.x] = (i < NN) ? cnt[i] : 0;
    __syncthreads();
    #pragma unroll
    for (int s = SCAN_B / 2; s > 0; s >>= 1) {
        if (threadIdx.x < s) sm[threadIdx.x] += sm[threadIdx.x + s];
        __syncthreads();
    }
    if (threadIdx.x == 0) part[blockIdx.x] = sm[0];
}

__global__ void s2_scan(int* __restrict__ part)
{
    if (threadIdx.x == 0 && blockIdx.x == 0) {
        int acc = 0;
        for (int b = 0; b < NSCAN; ++b) { int v = part[b]; part[b] = acc; acc += v; }
    }
}

__global__ __launch_bounds__(SCAN_B) void s3_offsets(const int* __restrict__ cnt,
                                                     const int* __restrict__ part,
                                                     int* __restrict__ offs,
                                                     int* __restrict__ cursor)
{
    __shared__ int sm[SCAN_B];
    int i = blockIdx.x * SCAN_B + threadIdx.x;
    int v = (i < NN) ? cnt[i] : 0;
    sm[threadIdx.x] = v;
    __syncthreads();
    #pragma unroll
    for (int s = 1; s < SCAN_B; s <<= 1) {
        int t = (threadIdx.x >= s) ? sm[threadIdx.x - s] : 0;
        __syncthreads();
        sm[threadIdx.x] += t;
        __syncthreads();
    }
    if (i < NN) {
        int ex = sm[threadIdx.x] - v + part[blockIdx.x];
        offs[i] = ex;
        cursor[i] = ex;
    }
}

__global__ __launch_bounds__(256) void fill_k(const int* __restrict__ edst,
                                              int* __restrict__ cursor,
                                              int* __restrict__ sorted)
{
    int e = blockIdx.x * 256 + threadIdx.x;
    if (e >= NE) return;
    int p = atomicAdd(&cursor[edst[e]], 1);
    sorted[p] = e;
}

// ---------------- kernel 1: node pre (s_scal, x1) ----------------
__global__ __launch_bounds__(256) void k1_nodes(
    const float* __restrict__ node_input, const float* __restrict__ node_attr,
    const float* __restrict__ W_sc1, const float* __restrict__ W_lin1_1,
    float* __restrict__ x1, float* __restrict__ ssc)
{
    int n = blockIdx.x * 256 + threadIdx.x;
    if (n >= NN) return;

    float ni[16];
    {
        const float4* p = reinterpret_cast<const float4*>(node_input + (size_t)n * 16);
        #pragma unroll
        for (int q = 0; q < 4; ++q) {
            float4 v = p[q];
            ni[q*4+0] = v.x; ni[q*4+1] = v.y; ni[q*4+2] = v.z; ni[q*4+3] = v.w;
        }
    }
    float sc = 0.25f * node_attr[n];

    float4* po = reinterpret_cast<float4*>(ssc + (size_t)n * 48);
    #pragma unroll
    for (int jb = 0; jb < 12; ++jb) {
        float a0 = 0.f, a1 = 0.f, a2 = 0.f, a3 = 0.f;
        #pragma unroll
        for (int u = 0; u < 16; ++u) {
            float x = ni[u]; const float* w = W_sc1 + u * 48 + jb * 4;
            a0 += x * w[0]; a1 += x * w[1]; a2 += x * w[2]; a3 += x * w[3];
        }
        float4 o; o.x = a0 * sc; o.y = a1 * sc; o.z = a2 * sc; o.w = a3 * sc;
        po[jb] = o;
    }
    float4* px = reinterpret_cast<float4*>(x1 + (size_t)n * 16);
    #pragma unroll
    for (int jb = 0; jb < 4; ++jb) {
        float a0 = 0.f, a1 = 0.f, a2 = 0.f, a3 = 0.f;
        #pragma unroll
        for (int u = 0; u < 16; ++u) {
            float x = ni[u]; const float* w = W_lin1_1 + u * 16 + jb * 4;
            a0 += x * w[0]; a1 += x * w[1]; a2 += x * w[2]; a3 += x * w[3];
        }
        float4 o; o.x = a0 * sc; o.y = a1 * sc; o.z = a2 * sc; o.w = a3 * sc;
        px[jb] = o;
    }
}

// ---------------- gather pass 1: per-node edge loop -> mid ----------------
__global__ __launch_bounds__(256) void g1_nodes(
    const float* __restrict__ ele, const float* __restrict__ eattr,
    const int* __restrict__ esrc,
    const int* __restrict__ offs, const int* __restrict__ cnt,
    const int* __restrict__ sorted,
    const float* __restrict__ fc1_W1, const float* __restrict__ fc1_W2,
    const float* __restrict__ x1, float* __restrict__ mid)
{
    int n = blockIdx.x * 256 + threadIdx.x;
    if (n >= NN) return;
    int start = offs[n], deg = cnt[n];

    float acc[64];
    #pragma unroll
    for (int i = 0; i < 64; ++i) acc[i] = 0.f;

    for (int t = 0; t < deg; ++t) {
        int e = sorted[start + t];
        int s = esrc[e];

        float el[10];
        {
            const float2* pe = reinterpret_cast<const float2*>(ele + (size_t)e * 10);
            #pragma unroll
            for (int q = 0; q < 5; ++q) {
                float2 v = pe[q];
                el[q*2+0] = v.x * INV_SQRT10; el[q*2+1] = v.y * INV_SQRT10;
            }
        }
        float h[64];
        #pragma unroll
        for (int jb = 0; jb < 16; ++jb) {
            float a0 = 0.f, a1 = 0.f, a2 = 0.f, a3 = 0.f;
            #pragma unroll
            for (int k = 0; k < 10; ++k) {
                float x = el[k]; const float* w = fc1_W1 + k * 64 + jb * 4;  // uniform -> s_load
                a0 += x * w[0]; a1 += x * w[1]; a2 += x * w[2]; a3 += x * w[3];
            }
            h[jb*4+0] = silu_f(a0); h[jb*4+1] = silu_f(a1);
            h[jb*4+2] = silu_f(a2); h[jb*4+3] = silu_f(a3);
        }

        float xs[16];
        {
            const float4* p = reinterpret_cast<const float4*>(x1 + (size_t)s * 16);
            #pragma unroll
            for (int q = 0; q < 4; ++q) {
                float4 v = p[q];
                xs[q*4+0] = v.x; xs[q*4+1] = v.y; xs[q*4+2] = v.z; xs[q*4+3] = v.w;
            }
        }
        float4 ea = reinterpret_cast<const float4*>(eattr)[e];

        #pragma unroll
        for (int jb = 0; jb < 8; ++jb) {
            float a0 = 0.f, a1 = 0.f, a2 = 0.f, a3 = 0.f;
            #pragma unroll
            for (int i = 0; i < 64; ++i) {
                float x = h[i]; const float* w = fc1_W2 + i * 32 + jb * 4;  // uniform -> s_load
                a0 += x * w[0]; a1 += x * w[1]; a2 += x * w[2]; a3 += x * w[3];
            }
            if (jb < 4) {
                int j = jb * 4;
                acc[j+0] += xs[j+0] * ea.x * a0;
                acc[j+1] += xs[j+1] * ea.x * a1;
                acc[j+2] += xs[j+2] * ea.x * a2;
                acc[j+3] += xs[j+3] * ea.x * a3;
            } else {
                int u = (jb - 4) * 4;
                float t0 = xs[u+0] * a0, t1 = xs[u+1] * a1;
                float t2 = xs[u+2] * a2, t3 = xs[u+3] * a3;
                acc[16+(u+0)*3+0] += t0 * ea.y; acc[16+(u+0)*3+1] += t0 * ea.z; acc[16+(u+0)*3+2] += t0 * ea.w;
                acc[16+(u+1)*3+0] += t1 * ea.y; acc[16+(u+1)*3+1] += t1 * ea.z; acc[16+(u+1)*3+2] += t1 * ea.w;
                acc[16+(u+2)*3+0] += t2 * ea.y; acc[16+(u+2)*3+1] += t2 * ea.z; acc[16+(u+2)*3+2] += t2 * ea.w;
                acc[16+(u+3)*3+0] += t3 * ea.y; acc[16+(u+3)*3+1] += t3 * ea.z; acc[16+(u+3)*3+2] += t3 * ea.w;
            }
        }
    }

    const float c = 0.125f * 0.25f;  // radial 1/sqrt(64) * segment 1/sqrt(16)
    float4* po = reinterpret_cast<float4*>(mid + (size_t)n * 64);
    #pragma unroll
    for (int q = 0; q < 16; ++q) {
        float4 o; o.x = acc[q*4+0]*c; o.y = acc[q*4+1]*c; o.z = acc[q*4+2]*c; o.w = acc[q*4+3]*c;
        po[q] = o;
    }
}

// ---------------- kernel 3: node mid (gates, h0, hv, s2) ----------------
__global__ __launch_bounds__(256) void k3_nodes(
    const float* __restrict__ node_attr, const float* __restrict__ ssc,
    const float* __restrict__ mid,
    const float* __restrict__ W_l2s, const float* __restrict__ W_l2v,
    const float* __restrict__ W_sc2, const float* __restrict__ W12s,
    const float* __restrict__ W12v,
    float* __restrict__ h0, float* __restrict__ hv, float* __restrict__ s2)
{
    int n = blockIdx.x * 256 + threadIdx.x;
    if (n >= NN) return;

    float na = node_attr[n];
    float m[64];
    {
        const float4* p = reinterpret_cast<const float4*>(mid + (size_t)n * 64);
        #pragma unroll
        for (int q = 0; q < 16; ++q) {
            float4 v = p[q];
            m[q*4+0] = v.x; m[q*4+1] = v.y; m[q*4+2] = v.z; m[q*4+3] = v.w;
        }
    }

    float scal[32], gates[16];
    const float4* pss = reinterpret_cast<const float4*>(ssc + (size_t)n * 48);
    #pragma unroll
    for (int jb = 0; jb < 12; ++jb) {
        float a0 = 0.f, a1 = 0.f, a2 = 0.f, a3 = 0.f;
        #pragma unroll
        for (int u = 0; u < 16; ++u) {
            float x = m[u]; const float* w = W_l2s + u * 48 + jb * 4;
            a0 += x * w[0]; a1 += x * w[1]; a2 += x * w[2]; a3 += x * w[3];
        }
        float4 sv = pss[jb];
        float cc = 0.25f * na;
        float g0 = C_S * sv.x + C_X * a0 * cc;
        float g1 = C_S * sv.y + C_X * a1 * cc;
        float g2 = C_S * sv.z + C_X * a2 * cc;
        float g3 = C_S * sv.w + C_X * a3 * cc;
        if (jb < 8) {
            int j = jb * 4;
            scal[j+0] = silu_f(g0); scal[j+1] = silu_f(g1);
            scal[j+2] = silu_f(g2); scal[j+3] = silu_f(g3);
        } else {
            int j = jb * 4 - 32;
            gates[j+0] = sigm_f(g0); gates[j+1] = sigm_f(g1);
            gates[j+2] = sigm_f(g2); gates[j+3] = sigm_f(g3);
        }
    }

    float vec[48];
    #pragma unroll
    for (int w = 0; w < 16; ++w) {
        float a0 = 0.f, a1 = 0.f, a2 = 0.f;
        #pragma unroll
        for (int u = 0; u < 16; ++u) {
            float wt = W_l2v[u * 16 + w];
            a0 += m[16 + u*3 + 0] * wt;
            a1 += m[16 + u*3 + 1] * wt;
            a2 += m[16 + u*3 + 2] * wt;
        }
        float gt = gates[w] * 0.25f * na;
        vec[w*3+0] = a0 * gt; vec[w*3+1] = a1 * gt; vec[w*3+2] = a2 * gt;
    }

    {
        float acc = 0.f;
        #pragma unroll
        for (int j = 0; j < 32; ++j) acc += scal[j] * W_sc2[j];
        s2[n] = acc * INV_SQRT32 * na;
    }

    {
        float c2 = INV_SQRT32 * na;
        float4* ph = reinterpret_cast<float4*>(h0 + (size_t)n * 32);
        #pragma unroll
        for (int jb = 0; jb < 8; ++jb) {
            float a0 = 0.f, a1 = 0.f, a2 = 0.f, a3 = 0.f;
            #pragma unroll
            for (int i = 0; i < 32; ++i) {
                float x = scal[i]; const float* w = W12s + i * 32 + jb * 4;
                a0 += x * w[0]; a1 += x * w[1]; a2 += x * w[2]; a3 += x * w[3];
            }
            float4 o; o.x = a0 * c2; o.y = a1 * c2; o.z = a2 * c2; o.w = a3 * c2;
            ph[jb] = o;
        }
    }

    {
        float c3 = 0.25f * na;
        float hvv[48];
        #pragma unroll
        for (int w = 0; w < 16; ++w) {
            float a0 = 0.f, a1 = 0.f, a2 = 0.f;
            #pragma unroll
            for (int u = 0; u < 16; ++u) {
                float wt = W12v[u * 16 + w];
                a0 += vec[u*3+0] * wt; a1 += vec[u*3+1] * wt; a2 += vec[u*3+2] * wt;
            }
            hvv[w*3+0] = a0 * c3; hvv[w*3+1] = a1 * c3; hvv[w*3+2] = a2 * c3;
        }
        float4* ph = reinterpret_cast<float4*>(hv + (size_t)n * 48);
        #pragma unroll
        for (int q = 0; q < 12; ++q) {
            float4 o; o.x = hvv[q*4+0]; o.y = hvv[q*4+1]; o.z = hvv[q*4+2]; o.w = hvv[q*4+3];
            ph[q] = o;
        }
    }
}

// ---------------- gather pass 2 (+ fused final linear) ----------------
__global__ __launch_bounds__(256) void g2_nodes(
    const float* __restrict__ ele, const float* __restrict__ eattr,
    const int* __restrict__ esrc,
    const int* __restrict__ offs, const int* __restrict__ cnt,
    const int* __restrict__ sorted,
    const float* __restrict__ fc2_W1, const float* __restrict__ fc2_W2,
    const float* __restrict__ h0, const float* __restrict__ hv,
    const float* __restrict__ node_attr, const float* __restrict__ s2,
    const float* __restrict__ W_lin2_2,
    float* __restrict__ out)
{
    int n = blockIdx.x * 256 + threadIdx.x;
    if (n >= NN) return;
    int start = offs[n], deg = cnt[n];

    float acc[48];
    #pragma unroll
    for (int i = 0; i < 48; ++i) acc[i] = 0.f;

    for (int t = 0; t < deg; ++t) {
        int e = sorted[start + t];
        int s = esrc[e];

        float el[10];
        {
            const float2* pe = reinterpret_cast<const float2*>(ele + (size_t)e * 10);
            #pragma unroll
            for (int q = 0; q < 5; ++q) {
                float2 v = pe[q];
                el[q*2+0] = v.x * INV_SQRT10; el[q*2+1] = v.y * INV_SQRT10;
            }
        }
        float h[64];
        #pragma unroll
        for (int jb = 0; jb < 16; ++jb) {
            float a0 = 0.f, a1 = 0.f, a2 = 0.f, a3 = 0.f;
            #pragma unroll
            for (int k = 0; k < 10; ++k) {
                float x = el[k]; const float* w = fc2_W1 + k * 64 + jb * 4;
                a0 += x * w[0]; a1 += x * w[1]; a2 += x * w[2]; a3 += x * w[3];
            }
            h[jb*4+0] = silu_f(a0); h[jb*4+1] = silu_f(a1);
            h[jb*4+2] = silu_f(a2); h[jb*4+3] = silu_f(a3);
        }

        float4 ea = reinterpret_cast<const float4*>(eattr)[e];

        // fa: g0 * ea0 * w2[:32]
        {
            float g0[32];
            const float4* p = reinterpret_cast<const float4*>(h0 + (size_t)s * 32);
            #pragma unroll
            for (int q = 0; q < 8; ++q) {
                float4 v = p[q];
                g0[q*4+0] = v.x * ea.x; g0[q*4+1] = v.y * ea.x;
                g0[q*4+2] = v.z * ea.x; g0[q*4+3] = v.w * ea.x;
            }
            #pragma unroll
            for (int jb = 0; jb < 8; ++jb) {
                float a0 = 0.f, a1 = 0.f, a2 = 0.f, a3 = 0.f;
                #pragma unroll
                for (int i = 0; i < 64; ++i) {
                    float x = h[i]; const float* w = fc2_W2 + i * 48 + jb * 4;
                    a0 += x * w[0]; a1 += x * w[1]; a2 += x * w[2]; a3 += x * w[3];
                }
                int j = jb * 4;
                acc[j+0] += g0[j+0] * a0; acc[j+1] += g0[j+1] * a1;
                acc[j+2] += g0[j+2] * a2; acc[j+3] += g0[j+3] * a3;
            }
        }

        // fb: dv * inv_sqrt3 * w2[32:48]
        {
            float dv[16];
            {
                float vv[48];
                const float4* p = reinterpret_cast<const float4*>(hv + (size_t)s * 48);
                #pragma unroll
                for (int q = 0; q < 12; ++q) {
                    float4 v = p[q];
                    vv[q*4+0] = v.x; vv[q*4+1] = v.y; vv[q*4+2] = v.z; vv[q*4+3] = v.w;
                }
                #pragma unroll
                for (int u = 0; u < 16; ++u)
                    dv[u] = (vv[u*3+0]*ea.y + vv[u*3+1]*ea.z + vv[u*3+2]*ea.w) * INV_SQRT3;
            }
            #pragma unroll
            for (int jb = 8; jb < 12; ++jb) {
                float a0 = 0.f, a1 = 0.f, a2 = 0.f, a3 = 0.f;
                #pragma unroll
                for (int i = 0; i < 64; ++i) {
                    float x = h[i]; const float* w = fc2_W2 + i * 48 + jb * 4;
                    a0 += x * w[0]; a1 += x * w[1]; a2 += x * w[2]; a3 += x * w[3];
                }
                int j = jb * 4; int u = j - 32;
                acc[j+0] += dv[u+0] * a0; acc[j+1] += dv[u+1] * a1;
                acc[j+2] += dv[u+2] * a2; acc[j+3] += dv[u+3] * a3;
            }
        }
    }

    // fused k5: out = C_S*s2 + C_X * (mid2 @ W_lin2_2) * inv(48) * na,  mid2 = acc*c
    const float c = 0.125f * 0.25f;
    float dot = 0.f;
    #pragma unroll
    for (int j = 0; j < 48; ++j) dot += acc[j] * W_lin2_2[j];
    out[n] = C_S * s2[n] + C_X * dot * c * INV_SQRT48 * node_attr[n];
}

extern "C" void kernel_launch(void* const* d_in, const int* in_sizes, int n_in,
                              void* d_out, int out_size, void* d_ws, size_t ws_size,
                              hipStream_t stream)
{
    const float* node_input = (const float*)d_in[0];
    const float* node_attr  = (const float*)d_in[1];
    const float* edge_attr  = (const float*)d_in[2];
    const float* ele        = (const float*)d_in[3];
    const float* W_sc1      = (const float*)d_in[4];
    const float* W_lin1_1   = (const float*)d_in[5];
    const float* fc1_W1     = (const float*)d_in[6];
    const float* fc1_W2     = (const float*)d_in[7];
    const float* W_l2s_1    = (const float*)d_in[8];
    const float* W_l2v_1    = (const float*)d_in[9];
    const float* W_sc2      = (const float*)d_in[10];
    const float* W_lin1_2s  = (const float*)d_in[11];
    const float* W_lin1_2v  = (const float*)d_in[12];
    const float* fc2_W1     = (const float*)d_in[13];
    const float* fc2_W2     = (const float*)d_in[14];
    const float* W_lin2_2   = (const float*)d_in[15];
    const int*   esrc       = (const int*)d_in[16];
    const int*   edst       = (const int*)d_in[17];
    float* out = (float*)d_out;
    float* wsf = (float*)d_ws;

    float* x1   = wsf + OFF_X1;
    float* ssc  = wsf + OFF_SS;
    float* mid  = wsf + OFF_MID;
    float* h0   = wsf + OFF_H0;
    float* hv   = wsf + OFF_HV;
    float* s2   = wsf + OFF_S2;
    int*   cnt    = (int*)(wsf + OFF_CNT);
    int*   offs   = (int*)(wsf + OFF_OFFS);
    int*   cursor = (int*)(wsf + OFF_CUR);
    int*   part   = (int*)(wsf + OFF_PART);
    int*   sorted = (int*)(wsf + OFF_SORT);

    hipMemsetAsync(cnt, 0, (size_t)NN * sizeof(int), stream);

    dim3 blk(256);
    int nodeGrid = (NN + 255) / 256;
    int edgeGrid = (NE + 255) / 256;

    // CSR build
    hist_k<<<edgeGrid, blk, 0, stream>>>(edst, cnt);
    s1_partial<<<NSCAN, SCAN_B, 0, stream>>>(cnt, part);
    s2_scan<<<1, 1, 0, stream>>>(part);
    s3_offsets<<<NSCAN, SCAN_B, 0, stream>>>(cnt, part, offs, cursor);
    fill_k<<<edgeGrid, blk, 0, stream>>>(edst, cursor, sorted);

    // network
    k1_nodes<<<nodeGrid, blk, 0, stream>>>(node_input, node_attr, W_sc1, W_lin1_1, x1, ssc);
    g1_nodes<<<nodeGrid, blk, 0, stream>>>(ele, edge_attr, esrc, offs, cnt, sorted,
                                           fc1_W1, fc1_W2, x1, mid);
    k3_nodes<<<nodeGrid, blk, 0, stream>>>(node_attr, ssc, mid, W_l2s_1, W_l2v_1, W_sc2,
                                           W_lin1_2s, W_lin1_2v, h0, hv, s2);
    g2_nodes<<<nodeGrid, blk, 0, stream>>>(ele, edge_attr, esrc, offs, cnt, sorted,
                                           fc2_W1, fc2_W2, h0, hv, node_attr, s2,
                                           W_lin2_2, out);
}

// Round 3
// 3399.891 us; speedup vs baseline: 2.8060x; 2.0424x over previous
//
#include <hip/hip_runtime.h>
#include <math.h>

#define NN 100000
#define NE 1600000

// ---- workspace layout (element offsets; all 4-byte elems) ----
// region reuse: MID (64N) holds `mid` until k3, then reused as `mid2` (48N)
#define OFF_X1   ((size_t)0)                  // N*16 f   [k1 -> e1]
#define OFF_SS   ((size_t)NN * 16)            // N*48 f   [k1 -> k3]
#define OFF_MID  ((size_t)NN * 64)            // N*64 f   [g1 -> k3], then N*48 mid2 [g2 -> k5]
#define OFF_H0   ((size_t)NN * 128)           // N*32 f   [k3 -> e2]
#define OFF_HV   ((size_t)NN * 160)           // N*48 f   [k3 -> e2]
#define OFF_S2   ((size_t)NN * 208)           // N    f   [k3 -> k5]
#define OFF_CNT  ((size_t)NN * 209)           // N    i
#define OFF_OFFS ((size_t)NN * 210)           // N    i
#define OFF_CUR  ((size_t)NN * 211)           // N    i
#define OFF_PART ((size_t)NN * 212)           // 128  i
#define OFF_SORT (OFF_PART + 128)             // E    i
#define OFF_EF   (OFF_SORT + (size_t)NE)      // edge-feature rows (adaptive capacity)

#define INV_SQRT10 0.31622776601683794f
#define INV_SQRT3  0.57735026918962576f
#define INV_SQRT32 0.17677669529663687f
#define INV_SQRT48 0.14433756729740643f
#define C_S 0.3826834323650898f
#define C_X 0.9238795325112867f

#define SCAN_B 1024
#define NSCAN ((NN + SCAN_B - 1) / SCAN_B)

__device__ __forceinline__ float silu_f(float x) { return x / (1.f + __expf(-x)); }
__device__ __forceinline__ float sigm_f(float x) { return 1.f / (1.f + __expf(-x)); }

// ---------------- CSR build ----------------
__global__ __launch_bounds__(256) void hist_k(const int* __restrict__ edst,
                                              int* __restrict__ cnt)
{
    int e = blockIdx.x * 256 + threadIdx.x;
    if (e >= NE) return;
    atomicAdd(&cnt[edst[e]], 1);
}

__global__ __launch_bounds__(SCAN_B) void s1_partial(const int* __restrict__ cnt,
                                                     int* __restrict__ part)
{
    __shared__ int sm[SCAN_B];
    int i = blockIdx.x * SCAN_B + threadIdx.x;
    sm[threadIdx.x] = (i < NN) ? cnt[i] : 0;
    __syncthreads();
    #pragma unroll
    for (int s = SCAN_B / 2; s > 0; s >>= 1) {
        if (threadIdx.x < s) sm[threadIdx.x] += sm[threadIdx.x + s];
        __syncthreads();
    }
    if (threadIdx.x == 0) part[blockIdx.x] = sm[0];
}

__global__ void s2_scan(int* __restrict__ part)
{
    if (threadIdx.x == 0 && blockIdx.x == 0) {
        int acc = 0;
        for (int b = 0; b < NSCAN; ++b) { int v = part[b]; part[b] = acc; acc += v; }
    }
}

__global__ __launch_bounds__(SCAN_B) void s3_offsets(const int* __restrict__ cnt,
                                                     const int* __restrict__ part,
                                                     int* __restrict__ offs,
                                                     int* __restrict__ cursor)
{
    __shared__ int sm[SCAN_B];
    int i = blockIdx.x * SCAN_B + threadIdx.x;
    int v = (i < NN) ? cnt[i] : 0;
    sm[threadIdx.x] = v;
    __syncthreads();
    #pragma unroll
    for (int s = 1; s < SCAN_B; s <<= 1) {
        int t = (threadIdx.x >= s) ? sm[threadIdx.x - s] : 0;
        __syncthreads();
        sm[threadIdx.x] += t;
        __syncthreads();
    }
    if (i < NN) {
        int ex = sm[threadIdx.x] - v + part[blockIdx.x];
        offs[i] = ex;
        cursor[i] = ex;
    }
}

__global__ __launch_bounds__(256) void fill_k(const int* __restrict__ edst,
                                              int* __restrict__ cursor,
                                              int* __restrict__ sorted)
{
    int e = blockIdx.x * 256 + threadIdx.x;
    if (e >= NE) return;
    int p = atomicAdd(&cursor[edst[e]], 1);
    sorted[p] = e;
}

// ---------------- kernel 1: node pre (s_scal, x1) ----------------
__global__ __launch_bounds__(256) void k1_nodes(
    const float* __restrict__ node_input, const float* __restrict__ node_attr,
    const float* __restrict__ W_sc1, const float* __restrict__ W_lin1_1,
    float* __restrict__ x1, float* __restrict__ ssc)
{
    int n = blockIdx.x * 256 + threadIdx.x;
    if (n >= NN) return;

    float ni[16];
    {
        const float4* p = reinterpret_cast<const float4*>(node_input + (size_t)n * 16);
        #pragma unroll
        for (int q = 0; q < 4; ++q) {
            float4 v = p[q];
            ni[q*4+0] = v.x; ni[q*4+1] = v.y; ni[q*4+2] = v.z; ni[q*4+3] = v.w;
        }
    }
    float sc = 0.25f * node_attr[n];

    float4* po = reinterpret_cast<float4*>(ssc + (size_t)n * 48);
    #pragma unroll
    for (int jb = 0; jb < 12; ++jb) {
        float a0 = 0.f, a1 = 0.f, a2 = 0.f, a3 = 0.f;
        #pragma unroll
        for (int u = 0; u < 16; ++u) {
            float x = ni[u]; const float* w = W_sc1 + u * 48 + jb * 4;
            a0 += x * w[0]; a1 += x * w[1]; a2 += x * w[2]; a3 += x * w[3];
        }
        float4 o; o.x = a0 * sc; o.y = a1 * sc; o.z = a2 * sc; o.w = a3 * sc;
        po[jb] = o;
    }
    float4* px = reinterpret_cast<float4*>(x1 + (size_t)n * 16);
    #pragma unroll
    for (int jb = 0; jb < 4; ++jb) {
        float a0 = 0.f, a1 = 0.f, a2 = 0.f, a3 = 0.f;
        #pragma unroll
        for (int u = 0; u < 16; ++u) {
            float x = ni[u]; const float* w = W_lin1_1 + u * 16 + jb * 4;
            a0 += x * w[0]; a1 += x * w[1]; a2 += x * w[2]; a3 += x * w[3];
        }
        float4 o; o.x = a0 * sc; o.y = a1 * sc; o.z = a2 * sc; o.w = a3 * sc;
        px[jb] = o;
    }
}

// ---------------- e1: edge-parallel pass-1 features (raw edge order) ----------------
__global__ __launch_bounds__(256) void e1_edges(
    const float* __restrict__ ele, const float* __restrict__ eattr,
    const int* __restrict__ esrc,
    const float* __restrict__ fc1_W1, const float* __restrict__ fc1_W2,
    const float* __restrict__ x1,
    float* __restrict__ ef, int base, int len)
{
    int i = blockIdx.x * 256 + threadIdx.x;
    if (i >= len) return;
    int e = base + i;

    float el[10];
    {
        const float2* pe = reinterpret_cast<const float2*>(ele + (size_t)e * 10);
        #pragma unroll
        for (int q = 0; q < 5; ++q) {
            float2 v = pe[q];
            el[q*2+0] = v.x * INV_SQRT10; el[q*2+1] = v.y * INV_SQRT10;
        }
    }
    float h[64];
    #pragma unroll
    for (int jb = 0; jb < 16; ++jb) {
        float a0 = 0.f, a1 = 0.f, a2 = 0.f, a3 = 0.f;
        #pragma unroll
        for (int k = 0; k < 10; ++k) {
            float x = el[k]; const float* w = fc1_W1 + k * 64 + jb * 4;  // uniform -> s_load
            a0 += x * w[0]; a1 += x * w[1]; a2 += x * w[2]; a3 += x * w[3];
        }
        h[jb*4+0] = silu_f(a0); h[jb*4+1] = silu_f(a1);
        h[jb*4+2] = silu_f(a2); h[jb*4+3] = silu_f(a3);
    }

    int s = esrc[e];
    float xs[16];
    {
        const float4* p = reinterpret_cast<const float4*>(x1 + (size_t)s * 16);
        #pragma unroll
        for (int q = 0; q < 4; ++q) {
            float4 v = p[q];
            xs[q*4+0] = v.x; xs[q*4+1] = v.y; xs[q*4+2] = v.z; xs[q*4+3] = v.w;
        }
    }
    float4 ea = reinterpret_cast<const float4*>(eattr)[e];

    const float c = 0.125f * 0.25f;  // radial 1/sqrt(64) * segment 1/sqrt(16)
    float* rp = ef + (size_t)i * 64;

    #pragma unroll
    for (int jb = 0; jb < 8; ++jb) {
        float a0 = 0.f, a1 = 0.f, a2 = 0.f, a3 = 0.f;
        #pragma unroll
        for (int k = 0; k < 64; ++k) {
            float x = h[k]; const float* w = fc1_W2 + k * 32 + jb * 4;  // uniform -> s_load
            a0 += x * w[0]; a1 += x * w[1]; a2 += x * w[2]; a3 += x * w[3];
        }
        if (jb < 4) {   // f0[j] = xs[j]*ea0*w[j]*c
            int j = jb * 4;
            float4 o;
            o.x = xs[j+0] * ea.x * a0 * c; o.y = xs[j+1] * ea.x * a1 * c;
            o.z = xs[j+2] * ea.x * a2 * c; o.w = xs[j+3] * ea.x * a3 * c;
            reinterpret_cast<float4*>(rp)[jb] = o;
        } else {        // f1[u][cc] = xs[u]*w[16+u]*ea1[cc]*c at row[16+u*3+cc]
            int u = (jb - 4) * 4;
            float t0 = xs[u+0] * a0 * c, t1 = xs[u+1] * a1 * c;
            float t2 = xs[u+2] * a2 * c, t3 = xs[u+3] * a3 * c;
            float4 v0, v1, v2;
            v0.x = t0*ea.y; v0.y = t0*ea.z; v0.z = t0*ea.w; v0.w = t1*ea.y;
            v1.x = t1*ea.z; v1.y = t1*ea.w; v1.z = t2*ea.y; v1.w = t2*ea.z;
            v2.x = t2*ea.w; v2.y = t3*ea.y; v2.z = t3*ea.z; v2.w = t3*ea.w;
            float4* pv = reinterpret_cast<float4*>(rp + 16 + u * 3);
            pv[0] = v0; pv[1] = v1; pv[2] = v2;
        }
    }
}

// ---------------- g1: wave-per-node row-sum (lane = channel) ----------------
__global__ __launch_bounds__(256) void g1_gather(
    const int* __restrict__ offs, const int* __restrict__ cnt,
    const int* __restrict__ sorted, const float* __restrict__ ef,
    int base, int len, float* __restrict__ mid)
{
    int gw = blockIdx.x * 4 + (threadIdx.x >> 6);
    int lane = threadIdx.x & 63;
    if (gw >= NN) return;
    int lo = offs[gw], deg = cnt[gw];

    float a = 0.f;
    bool any = false;
    for (int t = 0; t < deg; ++t) {
        int e = sorted[lo + t];                    // wave-uniform
        unsigned r = (unsigned)(e - base);
        if (r < (unsigned)len) {
            a += ef[(size_t)r * 64 + lane];        // coalesced 256B row
            any = true;
        }
    }
    if (any) mid[(size_t)gw * 64 + lane] += a;     // chunk-sequential RMW, wave-exclusive
}

// ---------------- kernel 3: node mid (gates, h0, hv, s2) ----------------
__global__ __launch_bounds__(256) void k3_nodes(
    const float* __restrict__ node_attr, const float* __restrict__ ssc,
    const float* __restrict__ mid,
    const float* __restrict__ W_l2s, const float* __restrict__ W_l2v,
    const float* __restrict__ W_sc2, const float* __restrict__ W12s,
    const float* __restrict__ W12v,
    float* __restrict__ h0, float* __restrict__ hv, float* __restrict__ s2)
{
    int n = blockIdx.x * 256 + threadIdx.x;
    if (n >= NN) return;

    float na = node_attr[n];
    float m[64];
    {
        const float4* p = reinterpret_cast<const float4*>(mid + (size_t)n * 64);
        #pragma unroll
        for (int q = 0; q < 16; ++q) {
            float4 v = p[q];
            m[q*4+0] = v.x; m[q*4+1] = v.y; m[q*4+2] = v.z; m[q*4+3] = v.w;
        }
    }

    float scal[32], gates[16];
    const float4* pss = reinterpret_cast<const float4*>(ssc + (size_t)n * 48);
    #pragma unroll
    for (int jb = 0; jb < 12; ++jb) {
        float a0 = 0.f, a1 = 0.f, a2 = 0.f, a3 = 0.f;
        #pragma unroll
        for (int u = 0; u < 16; ++u) {
            float x = m[u]; const float* w = W_l2s + u * 48 + jb * 4;
            a0 += x * w[0]; a1 += x * w[1]; a2 += x * w[2]; a3 += x * w[3];
        }
        float4 sv = pss[jb];
        float cc = 0.25f * na;
        float g0 = C_S * sv.x + C_X * a0 * cc;
        float g1 = C_S * sv.y + C_X * a1 * cc;
        float g2 = C_S * sv.z + C_X * a2 * cc;
        float g3 = C_S * sv.w + C_X * a3 * cc;
        if (jb < 8) {
            int j = jb * 4;
            scal[j+0] = silu_f(g0); scal[j+1] = silu_f(g1);
            scal[j+2] = silu_f(g2); scal[j+3] = silu_f(g3);
        } else {
            int j = jb * 4 - 32;
            gates[j+0] = sigm_f(g0); gates[j+1] = sigm_f(g1);
            gates[j+2] = sigm_f(g2); gates[j+3] = sigm_f(g3);
        }
    }

    float vec[48];
    #pragma unroll
    for (int w = 0; w < 16; ++w) {
        float a0 = 0.f, a1 = 0.f, a2 = 0.f;
        #pragma unroll
        for (int u = 0; u < 16; ++u) {
            float wt = W_l2v[u * 16 + w];
            a0 += m[16 + u*3 + 0] * wt;
            a1 += m[16 + u*3 + 1] * wt;
            a2 += m[16 + u*3 + 2] * wt;
        }
        float gt = gates[w] * 0.25f * na;
        vec[w*3+0] = a0 * gt; vec[w*3+1] = a1 * gt; vec[w*3+2] = a2 * gt;
    }

    {
        float acc = 0.f;
        #pragma unroll
        for (int j = 0; j < 32; ++j) acc += scal[j] * W_sc2[j];
        s2[n] = acc * INV_SQRT32 * na;
    }

    {
        float c2 = INV_SQRT32 * na;
        float4* ph = reinterpret_cast<float4*>(h0 + (size_t)n * 32);
        #pragma unroll
        for (int jb = 0; jb < 8; ++jb) {
            float a0 = 0.f, a1 = 0.f, a2 = 0.f, a3 = 0.f;
            #pragma unroll
            for (int k = 0; k < 32; ++k) {
                float x = scal[k]; const float* w = W12s + k * 32 + jb * 4;
                a0 += x * w[0]; a1 += x * w[1]; a2 += x * w[2]; a3 += x * w[3];
            }
            float4 o; o.x = a0 * c2; o.y = a1 * c2; o.z = a2 * c2; o.w = a3 * c2;
            ph[jb] = o;
        }
    }

    {
        float c3 = 0.25f * na;
        float hvv[48];
        #pragma unroll
        for (int w = 0; w < 16; ++w) {
            float a0 = 0.f, a1 = 0.f, a2 = 0.f;
            #pragma unroll
            for (int u = 0; u < 16; ++u) {
                float wt = W12v[u * 16 + w];
                a0 += vec[u*3+0] * wt; a1 += vec[u*3+1] * wt; a2 += vec[u*3+2] * wt;
            }
            hvv[w*3+0] = a0 * c3; hvv[w*3+1] = a1 * c3; hvv[w*3+2] = a2 * c3;
        }
        float4* ph = reinterpret_cast<float4*>(hv + (size_t)n * 48);
        #pragma unroll
        for (int q = 0; q < 12; ++q) {
            float4 o; o.x = hvv[q*4+0]; o.y = hvv[q*4+1]; o.z = hvv[q*4+2]; o.w = hvv[q*4+3];
            ph[q] = o;
        }
    }
}

// ---------------- e2: edge-parallel pass-2 features (raw edge order) ----------------
__global__ __launch_bounds__(256) void e2_edges(
    const float* __restrict__ ele, const float* __restrict__ eattr,
    const int* __restrict__ esrc,
    const float* __restrict__ fc2_W1, const float* __restrict__ fc2_W2,
    const float* __restrict__ h0, const float* __restrict__ hv,
    float* __restrict__ ef, int base, int len)
{
    int i = blockIdx.x * 256 + threadIdx.x;
    if (i >= len) return;
    int e = base + i;

    float el[10];
    {
        const float2* pe = reinterpret_cast<const float2*>(ele + (size_t)e * 10);
        #pragma unroll
        for (int q = 0; q < 5; ++q) {
            float2 v = pe[q];
            el[q*2+0] = v.x * INV_SQRT10; el[q*2+1] = v.y * INV_SQRT10;
        }
    }
    float h[64];
    #pragma unroll
    for (int jb = 0; jb < 16; ++jb) {
        float a0 = 0.f, a1 = 0.f, a2 = 0.f, a3 = 0.f;
        #pragma unroll
        for (int k = 0; k < 10; ++k) {
            float x = el[k]; const float* w = fc2_W1 + k * 64 + jb * 4;
            a0 += x * w[0]; a1 += x * w[1]; a2 += x * w[2]; a3 += x * w[3];
        }
        h[jb*4+0] = silu_f(a0); h[jb*4+1] = silu_f(a1);
        h[jb*4+2] = silu_f(a2); h[jb*4+3] = silu_f(a3);
    }

    int s = esrc[e];
    float4 ea = reinterpret_cast<const float4*>(eattr)[e];

    float g0[32];
    {
        const float4* p = reinterpret_cast<const float4*>(h0 + (size_t)s * 32);
        #pragma unroll
        for (int q = 0; q < 8; ++q) {
            float4 v = p[q];
            g0[q*4+0] = v.x * ea.x; g0[q*4+1] = v.y * ea.x;
            g0[q*4+2] = v.z * ea.x; g0[q*4+3] = v.w * ea.x;
        }
    }
    float dv[16];
    {
        const float4* p = reinterpret_cast<const float4*>(hv + (size_t)s * 48);
        float vv[48];
        #pragma unroll
        for (int q = 0; q < 12; ++q) {
            float4 v = p[q];
            vv[q*4+0] = v.x; vv[q*4+1] = v.y; vv[q*4+2] = v.z; vv[q*4+3] = v.w;
        }
        #pragma unroll
        for (int u = 0; u < 16; ++u)
            dv[u] = (vv[u*3+0]*ea.y + vv[u*3+1]*ea.z + vv[u*3+2]*ea.w) * INV_SQRT3;
    }

    const float c = 0.125f * 0.25f;
    float* rp = ef + (size_t)i * 48;
    #pragma unroll
    for (int jb = 0; jb < 12; ++jb) {
        float a0 = 0.f, a1 = 0.f, a2 = 0.f, a3 = 0.f;
        #pragma unroll
        for (int k = 0; k < 64; ++k) {
            float x = h[k]; const float* w = fc2_W2 + k * 48 + jb * 4;
            a0 += x * w[0]; a1 += x * w[1]; a2 += x * w[2]; a3 += x * w[3];
        }
        int j = jb * 4;
        float4 o;
        if (jb < 8) {
            o.x = g0[j+0] * a0 * c; o.y = g0[j+1] * a1 * c;
            o.z = g0[j+2] * a2 * c; o.w = g0[j+3] * a3 * c;
        } else {
            int u = j - 32;
            o.x = dv[u+0] * a0 * c; o.y = dv[u+1] * a1 * c;
            o.z = dv[u+2] * a2 * c; o.w = dv[u+3] * a3 * c;
        }
        reinterpret_cast<float4*>(rp)[jb] = o;
    }
}

// ---------------- g2: wave-per-node row-sum (48 channels) ----------------
__global__ __launch_bounds__(256) void g2_gather(
    const int* __restrict__ offs, const int* __restrict__ cnt,
    const int* __restrict__ sorted, const float* __restrict__ ef,
    int base, int len, float* __restrict__ mid2)
{
    int gw = blockIdx.x * 4 + (threadIdx.x >> 6);
    int lane = threadIdx.x & 63;
    if (gw >= NN) return;
    int lo = offs[gw], deg = cnt[gw];

    float a = 0.f;
    bool any = false;
    for (int t = 0; t < deg; ++t) {
        int e = sorted[lo + t];
        unsigned r = (unsigned)(e - base);
        if (r < (unsigned)len) {
            if (lane < 48) a += ef[(size_t)r * 48 + lane];
            any = true;
        }
    }
    if (any && lane < 48) mid2[(size_t)gw * 48 + lane] += a;
}

// ---------------- kernel 5: node final ----------------
__global__ __launch_bounds__(256) void k5_nodes(
    const float* __restrict__ node_attr, const float* __restrict__ mid2,
    const float* __restrict__ W_lin2_2, const float* __restrict__ s2,
    float* __restrict__ out)
{
    int n = blockIdx.x * 256 + threadIdx.x;
    if (n >= NN) return;
    float acc = 0.f;
    const float4* p = reinterpret_cast<const float4*>(mid2 + (size_t)n * 48);
    #pragma unroll
    for (int q = 0; q < 12; ++q) {
        float4 v = p[q];
        acc += v.x * W_lin2_2[q*4+0] + v.y * W_lin2_2[q*4+1]
             + v.z * W_lin2_2[q*4+2] + v.w * W_lin2_2[q*4+3];
    }
    out[n] = C_S * s2[n] + C_X * acc * INV_SQRT48 * node_attr[n];
}

extern "C" void kernel_launch(void* const* d_in, const int* in_sizes, int n_in,
                              void* d_out, int out_size, void* d_ws, size_t ws_size,
                              hipStream_t stream)
{
    const float* node_input = (const float*)d_in[0];
    const float* node_attr  = (const float*)d_in[1];
    const float* edge_attr  = (const float*)d_in[2];
    const float* ele        = (const float*)d_in[3];
    const float* W_sc1      = (const float*)d_in[4];
    const float* W_lin1_1   = (const float*)d_in[5];
    const float* fc1_W1     = (const float*)d_in[6];
    const float* fc1_W2     = (const float*)d_in[7];
    const float* W_l2s_1    = (const float*)d_in[8];
    const float* W_l2v_1    = (const float*)d_in[9];
    const float* W_sc2      = (const float*)d_in[10];
    const float* W_lin1_2s  = (const float*)d_in[11];
    const float* W_lin1_2v  = (const float*)d_in[12];
    const float* fc2_W1     = (const float*)d_in[13];
    const float* fc2_W2     = (const float*)d_in[14];
    const float* W_lin2_2   = (const float*)d_in[15];
    const int*   esrc       = (const int*)d_in[16];
    const int*   edst       = (const int*)d_in[17];
    float* out = (float*)d_out;
    float* wsf = (float*)d_ws;

    float* x1   = wsf + OFF_X1;
    float* ssc  = wsf + OFF_SS;
    float* mid  = wsf + OFF_MID;     // 64N; later reused as mid2 (48N)
    float* mid2 = wsf + OFF_MID;
    float* h0   = wsf + OFF_H0;
    float* hv   = wsf + OFF_HV;
    float* s2   = wsf + OFF_S2;
    int*   cnt    = (int*)(wsf + OFF_CNT);
    int*   offs   = (int*)(wsf + OFF_OFFS);
    int*   cursor = (int*)(wsf + OFF_CUR);
    int*   part   = (int*)(wsf + OFF_PART);
    int*   sorted = (int*)(wsf + OFF_SORT);
    float* ef     = wsf + OFF_EF;

    // adaptive ef capacity from actual workspace size (deterministic per run)
    size_t total_f = ws_size / 4;
    size_t avail = (total_f > OFF_EF) ? (total_f - OFF_EF) : 0;
    long long C1 = (long long)(avail / 64); if (C1 > NE) C1 = NE; if (C1 < 1) C1 = 1;
    long long C2 = (long long)(avail / 48); if (C2 > NE) C2 = NE; if (C2 < 1) C2 = 1;

    dim3 blk(256);
    int nodeGrid  = (NN + 255) / 256;
    int edgeGrid  = (NE + 255) / 256;
    int waveGrid  = (NN + 3) / 4;          // 1 wave per node, 4 waves/block

    hipMemsetAsync(cnt, 0, (size_t)NN * sizeof(int), stream);
    hipMemsetAsync(mid, 0, (size_t)NN * 64 * sizeof(float), stream);

    // CSR build
    hist_k<<<edgeGrid, blk, 0, stream>>>(edst, cnt);
    s1_partial<<<NSCAN, SCAN_B, 0, stream>>>(cnt, part);
    s2_scan<<<1, 1, 0, stream>>>(part);
    s3_offsets<<<NSCAN, SCAN_B, 0, stream>>>(cnt, part, offs, cursor);
    fill_k<<<edgeGrid, blk, 0, stream>>>(edst, cursor, sorted);

    // node pre
    k1_nodes<<<nodeGrid, blk, 0, stream>>>(node_input, node_attr, W_sc1, W_lin1_1, x1, ssc);

    // pass 1: edge-parallel features + wave-per-node gather (chunked by ws capacity)
    for (long long b = 0; b < NE; b += C1) {
        int len = (int)((NE - b < C1) ? (NE - b) : C1);
        e1_edges<<<(len + 255) / 256, blk, 0, stream>>>(ele, edge_attr, esrc,
                                                        fc1_W1, fc1_W2, x1,
                                                        ef, (int)b, len);
        g1_gather<<<waveGrid, blk, 0, stream>>>(offs, cnt, sorted, ef, (int)b, len, mid);
    }

    // node mid
    k3_nodes<<<nodeGrid, blk, 0, stream>>>(node_attr, ssc, mid, W_l2s_1, W_l2v_1, W_sc2,
                                           W_lin1_2s, W_lin1_2v, h0, hv, s2);

    // mid region is dead now; reuse as mid2 (zero it in-stream)
    hipMemsetAsync(mid2, 0, (size_t)NN * 48 * sizeof(float), stream);

    // pass 2
    for (long long b = 0; b < NE; b += C2) {
        int len = (int)((NE - b < C2) ? (NE - b) : C2);
        e2_edges<<<(len + 255) / 256, blk, 0, stream>>>(ele, edge_attr, esrc,
                                                        fc2_W1, fc2_W2, h0, hv,
                                                        ef, (int)b, len);
        g2_gather<<<waveGrid, blk, 0, stream>>>(offs, cnt, sorted, ef, (int)b, len, mid2);
    }

    // final
    k5_nodes<<<nodeGrid, blk, 0, stream>>>(node_attr, mid2, W_lin2_2, s2, out);
}

// Round 4
// 2084.125 us; speedup vs baseline: 4.5774x; 1.6313x over previous
//
#include <hip/hip_runtime.h>
#include <math.h>

#define NN 100000
#define NE 1600000

// ---- workspace layout (element offsets; all 4-byte elems) ----
#define OFF_X1   ((size_t)0)                  // N*16 f   [k1 -> e1]
#define OFF_SS   ((size_t)NN * 16)            // N*48 f   [k1 -> k3]
#define OFF_MID  ((size_t)NN * 64)            // N*64 f   [g1 -> k3], then N*48 mid2 [g2 -> k5]
#define OFF_H0   ((size_t)NN * 128)           // N*32 f   [k3 -> e2]
#define OFF_HV   ((size_t)NN * 160)           // N*48 f   [k3 -> e2]
#define OFF_S2   ((size_t)NN * 208)           // N    f   [k3 -> k5]
#define OFF_CNT  ((size_t)NN * 209)           // N    i
#define OFF_OFFS ((size_t)NN * 210)           // N    i
#define OFF_CUR  ((size_t)NN * 211)           // N    i
#define OFF_PART ((size_t)NN * 212)           // 128  i
#define OFF_SORT (OFF_PART + 128)             // E    i
#define OFF_EF   (OFF_SORT + (size_t)NE)      // edge-feature rows (adaptive capacity)

#define INV_SQRT10 0.31622776601683794f
#define INV_SQRT3  0.57735026918962576f
#define INV_SQRT32 0.17677669529663687f
#define INV_SQRT48 0.14433756729740643f
#define C_S 0.3826834323650898f
#define C_X 0.9238795325112867f

#define SCAN_B 1024
#define NSCAN ((NN + SCAN_B - 1) / SCAN_B)

__device__ __forceinline__ float silu_f(float x) { return x / (1.f + __expf(-x)); }
__device__ __forceinline__ float sigm_f(float x) { return 1.f / (1.f + __expf(-x)); }

// ---------------- CSR build ----------------
__global__ __launch_bounds__(256) void hist_k(const int* __restrict__ edst,
                                              int* __restrict__ cnt)
{
    int e = blockIdx.x * 256 + threadIdx.x;
    if (e >= NE) return;
    atomicAdd(&cnt[edst[e]], 1);
}

__global__ __launch_bounds__(SCAN_B) void s1_partial(const int* __restrict__ cnt,
                                                     int* __restrict__ part)
{
    __shared__ int sm[SCAN_B];
    int i = blockIdx.x * SCAN_B + threadIdx.x;
    sm[threadIdx.x] = (i < NN) ? cnt[i] : 0;
    __syncthreads();
    #pragma unroll
    for (int s = SCAN_B / 2; s > 0; s >>= 1) {
        if (threadIdx.x < s) sm[threadIdx.x] += sm[threadIdx.x + s];
        __syncthreads();
    }
    if (threadIdx.x == 0) part[blockIdx.x] = sm[0];
}

__global__ void s2_scan(int* __restrict__ part)
{
    if (threadIdx.x == 0 && blockIdx.x == 0) {
        int acc = 0;
        for (int b = 0; b < NSCAN; ++b) { int v = part[b]; part[b] = acc; acc += v; }
    }
}

__global__ __launch_bounds__(SCAN_B) void s3_offsets(const int* __restrict__ cnt,
                                                     const int* __restrict__ part,
                                                     int* __restrict__ offs,
                                                     int* __restrict__ cursor)
{
    __shared__ int sm[SCAN_B];
    int i = blockIdx.x * SCAN_B + threadIdx.x;
    int v = (i < NN) ? cnt[i] : 0;
    sm[threadIdx.x] = v;
    __syncthreads();
    #pragma unroll
    for (int s = 1; s < SCAN_B; s <<= 1) {
        int t = (threadIdx.x >= s) ? sm[threadIdx.x - s] : 0;
        __syncthreads();
        sm[threadIdx.x] += t;
        __syncthreads();
    }
    if (i < NN) {
        int ex = sm[threadIdx.x] - v + part[blockIdx.x];
        offs[i] = ex;
        cursor[i] = ex;
    }
}

__global__ __launch_bounds__(256) void fill_k(const int* __restrict__ edst,
                                              int* __restrict__ cursor,
                                              int* __restrict__ sorted)
{
    int e = blockIdx.x * 256 + threadIdx.x;
    if (e >= NE) return;
    int p = atomicAdd(&cursor[edst[e]], 1);
    sorted[p] = e;
}

// ---------------- kernel 1: node pre (s_scal, x1) ----------------
__global__ __launch_bounds__(256) void k1_nodes(
    const float* __restrict__ node_input, const float* __restrict__ node_attr,
    const float* __restrict__ W_sc1, const float* __restrict__ W_lin1_1,
    float* __restrict__ x1, float* __restrict__ ssc)
{
    int n = blockIdx.x * 256 + threadIdx.x;
    if (n >= NN) return;

    float ni[16];
    {
        const float4* p = reinterpret_cast<const float4*>(node_input + (size_t)n * 16);
        #pragma unroll
        for (int q = 0; q < 4; ++q) {
            float4 v = p[q];
            ni[q*4+0] = v.x; ni[q*4+1] = v.y; ni[q*4+2] = v.z; ni[q*4+3] = v.w;
        }
    }
    float sc = 0.25f * node_attr[n];

    float4* po = reinterpret_cast<float4*>(ssc + (size_t)n * 48);
    #pragma unroll
    for (int jb = 0; jb < 12; ++jb) {
        float a0 = 0.f, a1 = 0.f, a2 = 0.f, a3 = 0.f;
        #pragma unroll
        for (int u = 0; u < 16; ++u) {
            float x = ni[u]; const float* w = W_sc1 + u * 48 + jb * 4;
            a0 += x * w[0]; a1 += x * w[1]; a2 += x * w[2]; a3 += x * w[3];
        }
        float4 o; o.x = a0 * sc; o.y = a1 * sc; o.z = a2 * sc; o.w = a3 * sc;
        po[jb] = o;
    }
    float4* px = reinterpret_cast<float4*>(x1 + (size_t)n * 16);
    #pragma unroll
    for (int jb = 0; jb < 4; ++jb) {
        float a0 = 0.f, a1 = 0.f, a2 = 0.f, a3 = 0.f;
        #pragma unroll
        for (int u = 0; u < 16; ++u) {
            float x = ni[u]; const float* w = W_lin1_1 + u * 16 + jb * 4;
            a0 += x * w[0]; a1 += x * w[1]; a2 += x * w[2]; a3 += x * w[3];
        }
        float4 o; o.x = a0 * sc; o.y = a1 * sc; o.z = a2 * sc; o.w = a3 * sc;
        px[jb] = o;
    }
}

// ---------------- e1: edge-parallel pass-1 features (k-chunked radial) ----------------
__global__ __launch_bounds__(256, 4) void e1_edges(
    const float* __restrict__ ele, const float* __restrict__ eattr,
    const int* __restrict__ esrc,
    const float* __restrict__ fc1_W1, const float* __restrict__ fc1_W2,
    const float* __restrict__ x1,
    float* __restrict__ ef, int base, int len)
{
    int i = blockIdx.x * 256 + threadIdx.x;
    if (i >= len) return;
    int e = base + i;

    float el[10];
    {
        const float2* pe = reinterpret_cast<const float2*>(ele + (size_t)e * 10);
        #pragma unroll
        for (int q = 0; q < 5; ++q) {
            float2 v = pe[q];
            el[q*2+0] = v.x * INV_SQRT10; el[q*2+1] = v.y * INV_SQRT10;
        }
    }

    // accw = silu(el@W1) @ W2, computed in k-chunks of 16 to bound liveness
    float accw[32];
    #pragma unroll
    for (int j = 0; j < 32; ++j) accw[j] = 0.f;

    #pragma unroll
    for (int kk = 0; kk < 4; ++kk) {
        float h16[16];
        #pragma unroll
        for (int jb = 0; jb < 4; ++jb) {
            float a0 = 0.f, a1 = 0.f, a2 = 0.f, a3 = 0.f;
            #pragma unroll
            for (int k = 0; k < 10; ++k) {
                float x = el[k];
                const float* w = fc1_W1 + k * 64 + kk * 16 + jb * 4;  // uniform
                a0 += x * w[0]; a1 += x * w[1]; a2 += x * w[2]; a3 += x * w[3];
            }
            h16[jb*4+0] = silu_f(a0); h16[jb*4+1] = silu_f(a1);
            h16[jb*4+2] = silu_f(a2); h16[jb*4+3] = silu_f(a3);
        }
        #pragma unroll
        for (int jb = 0; jb < 8; ++jb) {
            float a0 = accw[jb*4+0], a1 = accw[jb*4+1], a2 = accw[jb*4+2], a3 = accw[jb*4+3];
            #pragma unroll
            for (int t = 0; t < 16; ++t) {
                float x = h16[t];
                const float* w = fc1_W2 + (kk * 16 + t) * 32 + jb * 4;  // uniform
                a0 += x * w[0]; a1 += x * w[1]; a2 += x * w[2]; a3 += x * w[3];
            }
            accw[jb*4+0] = a0; accw[jb*4+1] = a1; accw[jb*4+2] = a2; accw[jb*4+3] = a3;
        }
    }

    int s = esrc[e];
    float xs[16];
    {
        const float4* p = reinterpret_cast<const float4*>(x1 + (size_t)s * 16);
        #pragma unroll
        for (int q = 0; q < 4; ++q) {
            float4 v = p[q];
            xs[q*4+0] = v.x; xs[q*4+1] = v.y; xs[q*4+2] = v.z; xs[q*4+3] = v.w;
        }
    }
    float4 ea = reinterpret_cast<const float4*>(eattr)[e];

    const float c = 0.125f * 0.25f;  // radial 1/sqrt(64) * segment 1/sqrt(16)
    float* rp = ef + (size_t)i * 64;

    // f0 rows [0,16)
    #pragma unroll
    for (int q = 0; q < 4; ++q) {
        float4 o;
        o.x = xs[q*4+0] * ea.x * accw[q*4+0] * c;
        o.y = xs[q*4+1] * ea.x * accw[q*4+1] * c;
        o.z = xs[q*4+2] * ea.x * accw[q*4+2] * c;
        o.w = xs[q*4+3] * ea.x * accw[q*4+3] * c;
        reinterpret_cast<float4*>(rp)[q] = o;
    }
    // f1 rows [16,64): row 16+u*3+cc = xs[u]*accw[16+u]*c*ea1[cc]
    #pragma unroll
    for (int g = 0; g < 4; ++g) {
        int u = g * 4;
        float t0 = xs[u+0] * accw[16+u+0] * c, t1 = xs[u+1] * accw[16+u+1] * c;
        float t2 = xs[u+2] * accw[16+u+2] * c, t3 = xs[u+3] * accw[16+u+3] * c;
        float4 v0, v1, v2;
        v0.x = t0*ea.y; v0.y = t0*ea.z; v0.z = t0*ea.w; v0.w = t1*ea.y;
        v1.x = t1*ea.z; v1.y = t1*ea.w; v1.z = t2*ea.y; v1.w = t2*ea.z;
        v2.x = t2*ea.w; v2.y = t3*ea.y; v2.z = t3*ea.z; v2.w = t3*ea.w;
        float4* pv = reinterpret_cast<float4*>(rp + 16 + u * 3);
        pv[0] = v0; pv[1] = v1; pv[2] = v2;
    }
}

// ---------------- g1: wave-per-node row-sum, 4 edges/iter, float4 lanes ----------------
__global__ __launch_bounds__(256) void g1_gather(
    const int* __restrict__ offs, const int* __restrict__ cnt,
    const int* __restrict__ sorted, const float* __restrict__ ef,
    int base, int len, float* __restrict__ mid)
{
    int gw = blockIdx.x * 4 + (threadIdx.x >> 6);
    int lane = threadIdx.x & 63;
    if (gw >= NN) return;
    int lo = offs[gw], deg = cnt[gw];
    int sub = lane >> 4;       // which of 4 concurrent edges
    int ch4 = lane & 15;       // float4 slot (64 ch = 16 * 4)

    float4 acc; acc.x = 0.f; acc.y = 0.f; acc.z = 0.f; acc.w = 0.f;
    for (int t = 0; t < deg; t += 4) {
        int idx = t + sub;
        if (idx < deg) {
            int e = sorted[lo + idx];
            unsigned r = (unsigned)(e - base);
            if (r < (unsigned)len) {
                float4 v = reinterpret_cast<const float4*>(ef + (size_t)r * 64)[ch4];
                acc.x += v.x; acc.y += v.y; acc.z += v.z; acc.w += v.w;
            }
        }
    }
    // reduce across the 4 sub-groups (lane ^ 16, lane ^ 32)
    acc.x += __shfl_xor(acc.x, 16, 64); acc.y += __shfl_xor(acc.y, 16, 64);
    acc.z += __shfl_xor(acc.z, 16, 64); acc.w += __shfl_xor(acc.w, 16, 64);
    acc.x += __shfl_xor(acc.x, 32, 64); acc.y += __shfl_xor(acc.y, 32, 64);
    acc.z += __shfl_xor(acc.z, 32, 64); acc.w += __shfl_xor(acc.w, 32, 64);

    if (lane < 16) {
        float4* mp = reinterpret_cast<float4*>(mid + (size_t)gw * 64);
        float4 v = mp[lane];
        v.x += acc.x; v.y += acc.y; v.z += acc.z; v.w += acc.w;
        mp[lane] = v;
    }
}

// ---------------- kernel 3: node mid (gates, h0, hv, s2) ----------------
__global__ __launch_bounds__(256) void k3_nodes(
    const float* __restrict__ node_attr, const float* __restrict__ ssc,
    const float* __restrict__ mid,
    const float* __restrict__ W_l2s, const float* __restrict__ W_l2v,
    const float* __restrict__ W_sc2, const float* __restrict__ W12s,
    const float* __restrict__ W12v,
    float* __restrict__ h0, float* __restrict__ hv, float* __restrict__ s2)
{
    int n = blockIdx.x * 256 + threadIdx.x;
    if (n >= NN) return;

    float na = node_attr[n];
    float m[64];
    {
        const float4* p = reinterpret_cast<const float4*>(mid + (size_t)n * 64);
        #pragma unroll
        for (int q = 0; q < 16; ++q) {
            float4 v = p[q];
            m[q*4+0] = v.x; m[q*4+1] = v.y; m[q*4+2] = v.z; m[q*4+3] = v.w;
        }
    }

    float scal[32], gates[16];
    const float4* pss = reinterpret_cast<const float4*>(ssc + (size_t)n * 48);
    #pragma unroll
    for (int jb = 0; jb < 12; ++jb) {
        float a0 = 0.f, a1 = 0.f, a2 = 0.f, a3 = 0.f;
        #pragma unroll
        for (int u = 0; u < 16; ++u) {
            float x = m[u]; const float* w = W_l2s + u * 48 + jb * 4;
            a0 += x * w[0]; a1 += x * w[1]; a2 += x * w[2]; a3 += x * w[3];
        }
        float4 sv = pss[jb];
        float cc = 0.25f * na;
        float g0 = C_S * sv.x + C_X * a0 * cc;
        float g1 = C_S * sv.y + C_X * a1 * cc;
        float g2 = C_S * sv.z + C_X * a2 * cc;
        float g3 = C_S * sv.w + C_X * a3 * cc;
        if (jb < 8) {
            int j = jb * 4;
            scal[j+0] = silu_f(g0); scal[j+1] = silu_f(g1);
            scal[j+2] = silu_f(g2); scal[j+3] = silu_f(g3);
        } else {
            int j = jb * 4 - 32;
            gates[j+0] = sigm_f(g0); gates[j+1] = sigm_f(g1);
            gates[j+2] = sigm_f(g2); gates[j+3] = sigm_f(g3);
        }
    }

    float vec[48];
    #pragma unroll
    for (int w = 0; w < 16; ++w) {
        float a0 = 0.f, a1 = 0.f, a2 = 0.f;
        #pragma unroll
        for (int u = 0; u < 16; ++u) {
            float wt = W_l2v[u * 16 + w];
            a0 += m[16 + u*3 + 0] * wt;
            a1 += m[16 + u*3 + 1] * wt;
            a2 += m[16 + u*3 + 2] * wt;
        }
        float gt = gates[w] * 0.25f * na;
        vec[w*3+0] = a0 * gt; vec[w*3+1] = a1 * gt; vec[w*3+2] = a2 * gt;
    }

    {
        float acc = 0.f;
        #pragma unroll
        for (int j = 0; j < 32; ++j) acc += scal[j] * W_sc2[j];
        s2[n] = acc * INV_SQRT32 * na;
    }

    {
        float c2 = INV_SQRT32 * na;
        float4* ph = reinterpret_cast<float4*>(h0 + (size_t)n * 32);
        #pragma unroll
        for (int jb = 0; jb < 8; ++jb) {
            float a0 = 0.f, a1 = 0.f, a2 = 0.f, a3 = 0.f;
            #pragma unroll
            for (int k = 0; k < 32; ++k) {
                float x = scal[k]; const float* w = W12s + k * 32 + jb * 4;
                a0 += x * w[0]; a1 += x * w[1]; a2 += x * w[2]; a3 += x * w[3];
            }
            float4 o; o.x = a0 * c2; o.y = a1 * c2; o.z = a2 * c2; o.w = a3 * c2;
            ph[jb] = o;
        }
    }

    {
        float c3 = 0.25f * na;
        float hvv[48];
        #pragma unroll
        for (int w = 0; w < 16; ++w) {
            float a0 = 0.f, a1 = 0.f, a2 = 0.f;
            #pragma unroll
            for (int u = 0; u < 16; ++u) {
                float wt = W12v[u * 16 + w];
                a0 += vec[u*3+0] * wt; a1 += vec[u*3+1] * wt; a2 += vec[u*3+2] * wt;
            }
            hvv[w*3+0] = a0 * c3; hvv[w*3+1] = a1 * c3; hvv[w*3+2] = a2 * c3;
        }
        float4* ph = reinterpret_cast<float4*>(hv + (size_t)n * 48);
        #pragma unroll
        for (int q = 0; q < 12; ++q) {
            float4 o; o.x = hvv[q*4+0]; o.y = hvv[q*4+1]; o.z = hvv[q*4+2]; o.w = hvv[q*4+3];
            ph[q] = o;
        }
    }
}

// ---------------- e2: edge-parallel pass-2 features (k-chunked radial) ----------------
__global__ __launch_bounds__(256, 4) void e2_edges(
    const float* __restrict__ ele, const float* __restrict__ eattr,
    const int* __restrict__ esrc,
    const float* __restrict__ fc2_W1, const float* __restrict__ fc2_W2,
    const float* __restrict__ h0, const float* __restrict__ hv,
    float* __restrict__ ef, int base, int len)
{
    int i = blockIdx.x * 256 + threadIdx.x;
    if (i >= len) return;
    int e = base + i;

    float el[10];
    {
        const float2* pe = reinterpret_cast<const float2*>(ele + (size_t)e * 10);
        #pragma unroll
        for (int q = 0; q < 5; ++q) {
            float2 v = pe[q];
            el[q*2+0] = v.x * INV_SQRT10; el[q*2+1] = v.y * INV_SQRT10;
        }
    }

    float accw[48];
    #pragma unroll
    for (int j = 0; j < 48; ++j) accw[j] = 0.f;

    #pragma unroll
    for (int kk = 0; kk < 4; ++kk) {
        float h16[16];
        #pragma unroll
        for (int jb = 0; jb < 4; ++jb) {
            float a0 = 0.f, a1 = 0.f, a2 = 0.f, a3 = 0.f;
            #pragma unroll
            for (int k = 0; k < 10; ++k) {
                float x = el[k];
                const float* w = fc2_W1 + k * 64 + kk * 16 + jb * 4;  // uniform
                a0 += x * w[0]; a1 += x * w[1]; a2 += x * w[2]; a3 += x * w[3];
            }
            h16[jb*4+0] = silu_f(a0); h16[jb*4+1] = silu_f(a1);
            h16[jb*4+2] = silu_f(a2); h16[jb*4+3] = silu_f(a3);
        }
        #pragma unroll
        for (int jb = 0; jb < 12; ++jb) {
            float a0 = accw[jb*4+0], a1 = accw[jb*4+1], a2 = accw[jb*4+2], a3 = accw[jb*4+3];
            #pragma unroll
            for (int t = 0; t < 16; ++t) {
                float x = h16[t];
                const float* w = fc2_W2 + (kk * 16 + t) * 48 + jb * 4;  // uniform
                a0 += x * w[0]; a1 += x * w[1]; a2 += x * w[2]; a3 += x * w[3];
            }
            accw[jb*4+0] = a0; accw[jb*4+1] = a1; accw[jb*4+2] = a2; accw[jb*4+3] = a3;
        }
    }

    int s = esrc[e];
    float4 ea = reinterpret_cast<const float4*>(eattr)[e];
    const float c = 0.125f * 0.25f;
    float* rp = ef + (size_t)i * 48;

    // fa cols [0,32): stream h0 row through float4
    {
        const float4* ph = reinterpret_cast<const float4*>(h0 + (size_t)s * 32);
        #pragma unroll
        for (int q = 0; q < 8; ++q) {
            float4 g = ph[q];
            float4 o;
            o.x = g.x * ea.x * accw[q*4+0] * c;
            o.y = g.y * ea.x * accw[q*4+1] * c;
            o.z = g.z * ea.x * accw[q*4+2] * c;
            o.w = g.w * ea.x * accw[q*4+3] * c;
            reinterpret_cast<float4*>(rp)[q] = o;
        }
    }
    // fb cols [32,48): dv built streaming from hv row
    {
        float dv[16];
        #pragma unroll
        for (int u = 0; u < 16; ++u) dv[u] = 0.f;
        const float4* pv = reinterpret_cast<const float4*>(hv + (size_t)s * 48);
        #pragma unroll
        for (int q = 0; q < 12; ++q) {
            float4 v = pv[q];
            {
                int pos = q*4+0; float w = (pos%3==0) ? ea.y : ((pos%3==1) ? ea.z : ea.w);
                dv[pos/3] += v.x * w;
            }
            {
                int pos = q*4+1; float w = (pos%3==0) ? ea.y : ((pos%3==1) ? ea.z : ea.w);
                dv[pos/3] += v.y * w;
            }
            {
                int pos = q*4+2; float w = (pos%3==0) ? ea.y : ((pos%3==1) ? ea.z : ea.w);
                dv[pos/3] += v.z * w;
            }
            {
                int pos = q*4+3; float w = (pos%3==0) ? ea.y : ((pos%3==1) ? ea.z : ea.w);
                dv[pos/3] += v.w * w;
            }
        }
        const float c2 = c * INV_SQRT3;
        #pragma unroll
        for (int q = 0; q < 4; ++q) {
            float4 o;
            o.x = dv[q*4+0] * accw[32+q*4+0] * c2;
            o.y = dv[q*4+1] * accw[32+q*4+1] * c2;
            o.z = dv[q*4+2] * accw[32+q*4+2] * c2;
            o.w = dv[q*4+3] * accw[32+q*4+3] * c2;
            reinterpret_cast<float4*>(rp)[8+q] = o;
        }
    }
}

// ---------------- g2: wave-per-node row-sum, 4 edges/iter (48 ch) ----------------
__global__ __launch_bounds__(256) void g2_gather(
    const int* __restrict__ offs, const int* __restrict__ cnt,
    const int* __restrict__ sorted, const float* __restrict__ ef,
    int base, int len, float* __restrict__ mid2)
{
    int gw = blockIdx.x * 4 + (threadIdx.x >> 6);
    int lane = threadIdx.x & 63;
    if (gw >= NN) return;
    int lo = offs[gw], deg = cnt[gw];
    int sub = lane >> 4;
    int ch4 = lane & 15;       // active if < 12 (48 ch = 12 * 4)

    float4 acc; acc.x = 0.f; acc.y = 0.f; acc.z = 0.f; acc.w = 0.f;
    for (int t = 0; t < deg; t += 4) {
        int idx = t + sub;
        if (idx < deg && ch4 < 12) {
            int e = sorted[lo + idx];
            unsigned r = (unsigned)(e - base);
            if (r < (unsigned)len) {
                float4 v = reinterpret_cast<const float4*>(ef + (size_t)r * 48)[ch4];
                acc.x += v.x; acc.y += v.y; acc.z += v.z; acc.w += v.w;
            }
        }
    }
    acc.x += __shfl_xor(acc.x, 16, 64); acc.y += __shfl_xor(acc.y, 16, 64);
    acc.z += __shfl_xor(acc.z, 16, 64); acc.w += __shfl_xor(acc.w, 16, 64);
    acc.x += __shfl_xor(acc.x, 32, 64); acc.y += __shfl_xor(acc.y, 32, 64);
    acc.z += __shfl_xor(acc.z, 32, 64); acc.w += __shfl_xor(acc.w, 32, 64);

    if (lane < 12) {
        float4* mp = reinterpret_cast<float4*>(mid2 + (size_t)gw * 48);
        float4 v = mp[lane];
        v.x += acc.x; v.y += acc.y; v.z += acc.z; v.w += acc.w;
        mp[lane] = v;
    }
}

// ---------------- kernel 5: node final ----------------
__global__ __launch_bounds__(256) void k5_nodes(
    const float* __restrict__ node_attr, const float* __restrict__ mid2,
    const float* __restrict__ W_lin2_2, const float* __restrict__ s2,
    float* __restrict__ out)
{
    int n = blockIdx.x * 256 + threadIdx.x;
    if (n >= NN) return;
    float acc = 0.f;
    const float4* p = reinterpret_cast<const float4*>(mid2 + (size_t)n * 48);
    #pragma unroll
    for (int q = 0; q < 12; ++q) {
        float4 v = p[q];
        acc += v.x * W_lin2_2[q*4+0] + v.y * W_lin2_2[q*4+1]
             + v.z * W_lin2_2[q*4+2] + v.w * W_lin2_2[q*4+3];
    }
    out[n] = C_S * s2[n] + C_X * acc * INV_SQRT48 * node_attr[n];
}

extern "C" void kernel_launch(void* const* d_in, const int* in_sizes, int n_in,
                              void* d_out, int out_size, void* d_ws, size_t ws_size,
                              hipStream_t stream)
{
    const float* node_input = (const float*)d_in[0];
    const float* node_attr  = (const float*)d_in[1];
    const float* edge_attr  = (const float*)d_in[2];
    const float* ele        = (const float*)d_in[3];
    const float* W_sc1      = (const float*)d_in[4];
    const float* W_lin1_1   = (const float*)d_in[5];
    const float* fc1_W1     = (const float*)d_in[6];
    const float* fc1_W2     = (const float*)d_in[7];
    const float* W_l2s_1    = (const float*)d_in[8];
    const float* W_l2v_1    = (const float*)d_in[9];
    const float* W_sc2      = (const float*)d_in[10];
    const float* W_lin1_2s  = (const float*)d_in[11];
    const float* W_lin1_2v  = (const float*)d_in[12];
    const float* fc2_W1     = (const float*)d_in[13];
    const float* fc2_W2     = (const float*)d_in[14];
    const float* W_lin2_2   = (const float*)d_in[15];
    const int*   esrc       = (const int*)d_in[16];
    const int*   edst       = (const int*)d_in[17];
    float* out = (float*)d_out;
    float* wsf = (float*)d_ws;

    float* x1   = wsf + OFF_X1;
    float* ssc  = wsf + OFF_SS;
    float* mid  = wsf + OFF_MID;     // 64N; later reused as mid2 (48N)
    float* mid2 = wsf + OFF_MID;
    float* h0   = wsf + OFF_H0;
    float* hv   = wsf + OFF_HV;
    float* s2   = wsf + OFF_S2;
    int*   cnt    = (int*)(wsf + OFF_CNT);
    int*   offs   = (int*)(wsf + OFF_OFFS);
    int*   cursor = (int*)(wsf + OFF_CUR);
    int*   part   = (int*)(wsf + OFF_PART);
    int*   sorted = (int*)(wsf + OFF_SORT);
    float* ef     = wsf + OFF_EF;

    // adaptive ef capacity from actual workspace size (deterministic per run)
    size_t total_f = ws_size / 4;
    size_t avail = (total_f > OFF_EF) ? (total_f - OFF_EF) : 0;
    long long C1 = (long long)(avail / 64); if (C1 > NE) C1 = NE; if (C1 < 1) C1 = 1;
    long long C2 = (long long)(avail / 48); if (C2 > NE) C2 = NE; if (C2 < 1) C2 = 1;

    dim3 blk(256);
    int nodeGrid  = (NN + 255) / 256;
    int edgeGrid  = (NE + 255) / 256;
    int waveGrid  = (NN + 3) / 4;          // 1 wave per node, 4 waves/block

    hipMemsetAsync(cnt, 0, (size_t)NN * sizeof(int), stream);
    hipMemsetAsync(mid, 0, (size_t)NN * 64 * sizeof(float), stream);

    // CSR build
    hist_k<<<edgeGrid, blk, 0, stream>>>(edst, cnt);
    s1_partial<<<NSCAN, SCAN_B, 0, stream>>>(cnt, part);
    s2_scan<<<1, 1, 0, stream>>>(part);
    s3_offsets<<<NSCAN, SCAN_B, 0, stream>>>(cnt, part, offs, cursor);
    fill_k<<<edgeGrid, blk, 0, stream>>>(edst, cursor, sorted);

    // node pre
    k1_nodes<<<nodeGrid, blk, 0, stream>>>(node_input, node_attr, W_sc1, W_lin1_1, x1, ssc);

    // pass 1: edge-parallel features + wave-per-node gather (chunked by ws capacity)
    for (long long b = 0; b < NE; b += C1) {
        int len = (int)((NE - b < C1) ? (NE - b) : C1);
        e1_edges<<<(len + 255) / 256, blk, 0, stream>>>(ele, edge_attr, esrc,
                                                        fc1_W1, fc1_W2, x1,
                                                        ef, (int)b, len);
        g1_gather<<<waveGrid, blk, 0, stream>>>(offs, cnt, sorted, ef, (int)b, len, mid);
    }

    // node mid
    k3_nodes<<<nodeGrid, blk, 0, stream>>>(node_attr, ssc, mid, W_l2s_1, W_l2v_1, W_sc2,
                                           W_lin1_2s, W_lin1_2v, h0, hv, s2);

    // mid region dead; reuse as mid2
    hipMemsetAsync(mid2, 0, (size_t)NN * 48 * sizeof(float), stream);

    // pass 2
    for (long long b = 0; b < NE; b += C2) {
        int len = (int)((NE - b < C2) ? (NE - b) : C2);
        e2_edges<<<(len + 255) / 256, blk, 0, stream>>>(ele, edge_attr, esrc,
                                                        fc2_W1, fc2_W2, h0, hv,
                                                        ef, (int)b, len);
        g2_gather<<<waveGrid, blk, 0, stream>>>(offs, cnt, sorted, ef, (int)b, len, mid2);
    }

    // final
    k5_nodes<<<nodeGrid, blk, 0, stream>>>(node_attr, mid2, W_lin2_2, s2, out);
}

// Round 6
// 1376.312 us; speedup vs baseline: 6.9315x; 1.5143x over previous
//
#include <hip/hip_runtime.h>
#include <math.h>

#define NN 100000
#define NE 1600000

typedef __attribute__((ext_vector_type(8))) short bf16x8;
typedef __attribute__((ext_vector_type(4))) float f32x4;

// ---- workspace layout (element offsets; all 4-byte elems) ----
#define OFF_X1    ((size_t)0)                    // N*16 f
#define OFF_SS    ((size_t)NN * 16)              // N*48 f
#define OFF_MID   ((size_t)NN * 64)              // N*64 f (then N*48 mid2)
#define OFF_H0    ((size_t)NN * 128)             // N*32 f
#define OFF_HV    ((size_t)NN * 160)             // N*48 f
#define OFF_S2    ((size_t)NN * 208)             // N    f
#define OFF_CNT   ((size_t)NN * 209)             // N    i
#define OFF_OFFS  ((size_t)NN * 210)             // N    i
#define OFF_CUR   ((size_t)NN * 211)             // N    i
#define OFF_PART  ((size_t)NN * 212)             // 128  i
#define OFF_SORT  (OFF_PART + 128)               // E    i
#define OFF_ELEP  (OFF_SORT + (size_t)NE)        // E*5  u32 (bf16-pair el, pre-scaled)
#define OFF_EATP  (OFF_ELEP + (size_t)NE * 5)    // E*4  f
#define OFF_ESRCP (OFF_EATP + (size_t)NE * 4)    // E    i
#define OFF_EF    (OFF_ESRCP + (size_t)NE)       // edge-feature rows (adaptive)

#define INV_SQRT10 0.31622776601683794f
#define INV_SQRT3  0.57735026918962576f
#define INV_SQRT32 0.17677669529663687f
#define INV_SQRT48 0.14433756729740643f
#define C_S 0.3826834323650898f
#define C_X 0.9238795325112867f

#define SCAN_B 1024
#define NSCAN ((NN + SCAN_B - 1) / SCAN_B)

__device__ __forceinline__ float silu_f(float x) { return x / (1.f + __expf(-x)); }
__device__ __forceinline__ float sigm_f(float x) { return 1.f / (1.f + __expf(-x)); }

__device__ __forceinline__ unsigned short cvt_bf16(float a) {
    unsigned u = __float_as_uint(a);
    u = (u + 0x7fffu + ((u >> 16) & 1u)) >> 16;
    return (unsigned short)u;
}
__device__ __forceinline__ unsigned cvt2_bf16(float a, float b) {
    return (unsigned)cvt_bf16(a) | ((unsigned)cvt_bf16(b) << 16);
}
__device__ __forceinline__ float blo(unsigned u) { return __uint_as_float(u << 16); }
__device__ __forceinline__ float bhi(unsigned u) { return __uint_as_float(u & 0xffff0000u); }

// ---------------- CSR build ----------------
__global__ __launch_bounds__(256) void hist_k(const int* __restrict__ edst,
                                              int* __restrict__ cnt)
{
    int e = blockIdx.x * 256 + threadIdx.x;
    if (e >= NE) return;
    atomicAdd(&cnt[edst[e]], 1);
}

__global__ __launch_bounds__(SCAN_B) void s1_partial(const int* __restrict__ cnt,
                                                     int* __restrict__ part)
{
    __shared__ int sm[SCAN_B];
    int i = blockIdx.x * SCAN_B + threadIdx.x;
    sm[threadIdx.x] = (i < NN) ? cnt[i] : 0;
    __syncthreads();
    #pragma unroll
    for (int s = SCAN_B / 2; s > 0; s >>= 1) {
        if (threadIdx.x < s) sm[threadIdx.x] += sm[threadIdx.x + s];
        __syncthreads();
    }
    if (threadIdx.x == 0) part[blockIdx.x] = sm[0];
}

__global__ void s2_scan(int* __restrict__ part)
{
    if (threadIdx.x == 0 && blockIdx.x == 0) {
        int acc = 0;
        for (int b = 0; b < NSCAN; ++b) { int v = part[b]; part[b] = acc; acc += v; }
    }
}

__global__ __launch_bounds__(SCAN_B) void s3_offsets(const int* __restrict__ cnt,
                                                     const int* __restrict__ part,
                                                     int* __restrict__ offs,
                                                     int* __restrict__ cursor)
{
    __shared__ int sm[SCAN_B];
    int i = blockIdx.x * SCAN_B + threadIdx.x;
    int v = (i < NN) ? cnt[i] : 0;
    sm[threadIdx.x] = v;
    __syncthreads();
    #pragma unroll
    for (int s = 1; s < SCAN_B; s <<= 1) {
        int t = (threadIdx.x >= s) ? sm[threadIdx.x - s] : 0;
        __syncthreads();
        sm[threadIdx.x] += t;
        __syncthreads();
    }
    if (i < NN) {
        int ex = sm[threadIdx.x] - v + part[blockIdx.x];
        offs[i] = ex;
        cursor[i] = ex;
    }
}

__global__ __launch_bounds__(256) void fill_k(const int* __restrict__ edst,
                                              int* __restrict__ cursor,
                                              int* __restrict__ sorted)
{
    int e = blockIdx.x * 256 + threadIdx.x;
    if (e >= NE) return;
    int p = atomicAdd(&cursor[edst[e]], 1);
    sorted[p] = e;
}

// ---------------- permute edge data into CSR slot order ----------------
__global__ __launch_bounds__(256) void permute_k(
    const int* __restrict__ sorted,
    const float* __restrict__ ele, const float* __restrict__ eattr,
    const int* __restrict__ esrc,
    unsigned* __restrict__ elep, float4* __restrict__ eatp,
    int* __restrict__ esrcp)
{
    int i = blockIdx.x * 256 + threadIdx.x;
    if (i >= NE) return;
    int e = sorted[i];
    const float2* pe = reinterpret_cast<const float2*>(ele + (size_t)e * 10);
    unsigned* po = elep + (size_t)i * 5;
    #pragma unroll
    for (int q = 0; q < 5; ++q) {
        float2 v = pe[q];
        po[q] = cvt2_bf16(v.x * INV_SQRT10, v.y * INV_SQRT10);
    }
    eatp[i] = reinterpret_cast<const float4*>(eattr)[e];
    esrcp[i] = esrc[e];
}

// ---------------- kernel 1: node pre (s_scal, x1) ----------------
__global__ __launch_bounds__(256) void k1_nodes(
    const float* __restrict__ node_input, const float* __restrict__ node_attr,
    const float* __restrict__ W_sc1, const float* __restrict__ W_lin1_1,
    float* __restrict__ x1, float* __restrict__ ssc)
{
    int n = blockIdx.x * 256 + threadIdx.x;
    if (n >= NN) return;

    float ni[16];
    {
        const float4* p = reinterpret_cast<const float4*>(node_input + (size_t)n * 16);
        #pragma unroll
        for (int q = 0; q < 4; ++q) {
            float4 v = p[q];
            ni[q*4+0] = v.x; ni[q*4+1] = v.y; ni[q*4+2] = v.z; ni[q*4+3] = v.w;
        }
    }
    float sc = 0.25f * node_attr[n];

    float4* po = reinterpret_cast<float4*>(ssc + (size_t)n * 48);
    #pragma unroll
    for (int jb = 0; jb < 12; ++jb) {
        float a0 = 0.f, a1 = 0.f, a2 = 0.f, a3 = 0.f;
        #pragma unroll
        for (int u = 0; u < 16; ++u) {
            float x = ni[u]; const float* w = W_sc1 + u * 48 + jb * 4;
            a0 += x * w[0]; a1 += x * w[1]; a2 += x * w[2]; a3 += x * w[3];
        }
        float4 o; o.x = a0 * sc; o.y = a1 * sc; o.z = a2 * sc; o.w = a3 * sc;
        po[jb] = o;
    }
    float4* px = reinterpret_cast<float4*>(x1 + (size_t)n * 16);
    #pragma unroll
    for (int jb = 0; jb < 4; ++jb) {
        float a0 = 0.f, a1 = 0.f, a2 = 0.f, a3 = 0.f;
        #pragma unroll
        for (int u = 0; u < 16; ++u) {
            float x = ni[u]; const float* w = W_lin1_1 + u * 16 + jb * 4;
            a0 += x * w[0]; a1 += x * w[1]; a2 += x * w[2]; a3 += x * w[3];
        }
        float4 o; o.x = a0 * sc; o.y = a1 * sc; o.z = a2 * sc; o.w = a3 * sc;
        px[jb] = o;
    }
}

// ================= MFMA edge kernels =================
// LDS layout (bytes), swizzled 16B slots: phys_slot = slot ^ (row & 7)
//   W1T: 64 rows x 128B  (W1^T, k padded to 32, rest of row unused)
//   W2T: NW2 rows x 128B (W2^T, k = 64)
//   H  : 256 rows x 128B (layer1 act bf16[64]; reused as Wout bf16 rows)

__device__ __forceinline__ void stage_w1t(const float* __restrict__ W1,
                                          unsigned char* lds, int W1T_OFF, int ncols)
{
    // W1 global [10][ncols]; W1T row r=col, k in [0,32)
    for (int idx = threadIdx.x; idx < ncols * 32; idx += 256) {
        int r = idx >> 5, k = idx & 31;
        float v = (k < 10) ? W1[k * ncols + r] : 0.f;
        int addr = W1T_OFF + r * 128 + (((k >> 3) ^ (r & 7)) << 4) + ((k & 7) << 1);
        *reinterpret_cast<unsigned short*>(lds + addr) = cvt_bf16(v);
    }
}

__device__ __forceinline__ void stage_w2t(const float* __restrict__ W2,
                                          unsigned char* lds, int W2T_OFF, int ncols)
{
    // W2 global [64][ncols]; W2T row r=col, k in [0,64)
    for (int idx = threadIdx.x; idx < ncols * 64; idx += 256) {
        int r = idx >> 6, k = idx & 63;
        float v = W2[k * ncols + r];
        int addr = W2T_OFF + r * 128 + (((k >> 3) ^ (r & 7)) << 4) + ((k & 7) << 1);
        *reinterpret_cast<unsigned short*>(lds + addr) = cvt_bf16(v);
    }
}

// ---------------- e1: MFMA edge pass 1 ----------------
#define E1_W1T 0
#define E1_W2T 8192
#define E1_H   (8192 + 4096)
__global__ __launch_bounds__(256) void e1_mfma(
    const unsigned* __restrict__ elep, const float4* __restrict__ eatp,
    const int* __restrict__ esrcp,
    const float* __restrict__ fc1_W1, const float* __restrict__ fc1_W2,
    const float* __restrict__ x1,
    float* __restrict__ ef, int base, int len)
{
    __shared__ __align__(16) unsigned char lds[8192 + 4096 + 32768];
    stage_w1t(fc1_W1, lds, E1_W1T, 64);
    stage_w2t(fc1_W2, lds, E1_W2T, 32);

    int tid = threadIdx.x;
    int i = blockIdx.x * 256 + tid;       // local slot in chunk
    int lane = tid & 63, wv = tid >> 6;
    int kk = lane >> 4, l15 = lane & 15;

    unsigned ep[5];
    if (i < len) {
        const unsigned* pe = elep + (size_t)(base + i) * 5;
        #pragma unroll
        for (int q = 0; q < 5; ++q) ep[q] = pe[q];
    } else {
        #pragma unroll
        for (int q = 0; q < 5; ++q) ep[q] = 0u;
    }
    __syncthreads();

    // ---- layer 1: h = silu(el @ W1), write bf16 H ----
    #pragma unroll
    for (int mt = 0; mt < 4; ++mt) {
        int sl = mt * 16 + l15;
        int v0 = __shfl((int)ep[0], sl, 64);
        int v1 = __shfl((int)ep[1], sl, 64);
        int v2 = __shfl((int)ep[2], sl, 64);
        int v3 = __shfl((int)ep[3], sl, 64);
        int v4 = __shfl((int)ep[4], sl, 64);
        union { int u[4]; bf16x8 v; } au;
        au.u[0] = (kk == 0) ? v0 : ((kk == 1) ? v4 : 0);
        au.u[1] = (kk == 0) ? v1 : 0;
        au.u[2] = (kk == 0) ? v2 : 0;
        au.u[3] = (kk == 0) ? v3 : 0;
        bf16x8 afrag = au.v;
        #pragma unroll
        for (int nt = 0; nt < 4; ++nt) {
            int r = nt * 16 + l15;
            bf16x8 bfrag = *reinterpret_cast<const bf16x8*>(
                lds + E1_W1T + r * 128 + ((kk ^ (r & 7)) << 4));
            f32x4 acc = {0.f, 0.f, 0.f, 0.f};
            acc = __builtin_amdgcn_mfma_f32_16x16x32_bf16(afrag, bfrag, acc, 0, 0, 0);
            #pragma unroll
            for (int r4 = 0; r4 < 4; ++r4) {
                int row = wv * 64 + mt * 16 + kk * 4 + r4;
                int col = nt * 16 + l15;
                int addr = E1_H + row * 128 + ((((col >> 3) ^ (row & 7))) << 4) + ((col & 7) << 1);
                *reinterpret_cast<unsigned short*>(lds + addr) = cvt_bf16(silu_f(acc[r4]));
            }
        }
    }
    __syncthreads();

    // ---- layer 2: w = H @ W2  (N=32) ----
    f32x4 acc2[4][2];
    #pragma unroll
    for (int mt = 0; mt < 4; ++mt)
        #pragma unroll
        for (int nt = 0; nt < 2; ++nt) acc2[mt][nt] = (f32x4){0.f, 0.f, 0.f, 0.f};

    #pragma unroll
    for (int ks = 0; ks < 2; ++ks) {
        int slot = ks * 4 + kk;
        bf16x8 bfr[2];
        #pragma unroll
        for (int nt = 0; nt < 2; ++nt) {
            int r = nt * 16 + l15;
            bfr[nt] = *reinterpret_cast<const bf16x8*>(
                lds + E1_W2T + r * 128 + ((slot ^ (r & 7)) << 4));
        }
        #pragma unroll
        for (int mt = 0; mt < 4; ++mt) {
            int row = wv * 64 + mt * 16 + l15;
            bf16x8 a = *reinterpret_cast<const bf16x8*>(
                lds + E1_H + row * 128 + ((slot ^ (row & 7)) << 4));
            #pragma unroll
            for (int nt = 0; nt < 2; ++nt)
                acc2[mt][nt] = __builtin_amdgcn_mfma_f32_16x16x32_bf16(a, bfr[nt], acc2[mt][nt], 0, 0, 0);
        }
    }
    __syncthreads();

    // ---- store w rows (bf16) into H region ----
    #pragma unroll
    for (int mt = 0; mt < 4; ++mt)
        #pragma unroll
        for (int nt = 0; nt < 2; ++nt)
            #pragma unroll
            for (int r4 = 0; r4 < 4; ++r4) {
                int row = wv * 64 + mt * 16 + kk * 4 + r4;
                int col = nt * 16 + l15;
                int addr = E1_H + row * 128 + ((((col >> 3) ^ (row & 7))) << 4) + ((col & 7) << 1);
                *reinterpret_cast<unsigned short*>(lds + addr) = cvt_bf16(acc2[mt][nt][r4]);
            }
    __syncthreads();

    // ---- epilogue: per-thread assemble ef row ----
    if (i >= len) return;
    float w[32];
    #pragma unroll
    for (int s6 = 0; s6 < 4; ++s6) {
        uint4 t4 = *reinterpret_cast<const uint4*>(
            lds + E1_H + tid * 128 + ((s6 ^ (tid & 7)) << 4));
        w[s6*8+0] = blo(t4.x); w[s6*8+1] = bhi(t4.x);
        w[s6*8+2] = blo(t4.y); w[s6*8+3] = bhi(t4.y);
        w[s6*8+4] = blo(t4.z); w[s6*8+5] = bhi(t4.z);
        w[s6*8+6] = blo(t4.w); w[s6*8+7] = bhi(t4.w);
    }
    int s = esrcp[base + i];
    float4 ea = eatp[base + i];
    float xs[16];
    {
        const float4* p = reinterpret_cast<const float4*>(x1 + (size_t)s * 16);
        #pragma unroll
        for (int q = 0; q < 4; ++q) {
            float4 v = p[q];
            xs[q*4+0] = v.x; xs[q*4+1] = v.y; xs[q*4+2] = v.z; xs[q*4+3] = v.w;
        }
    }
    const float c = 0.125f * 0.25f;
    float* rp = ef + (size_t)i * 64;
    #pragma unroll
    for (int q = 0; q < 4; ++q) {
        float4 o;
        o.x = xs[q*4+0] * ea.x * w[q*4+0] * c;
        o.y = xs[q*4+1] * ea.x * w[q*4+1] * c;
        o.z = xs[q*4+2] * ea.x * w[q*4+2] * c;
        o.w = xs[q*4+3] * ea.x * w[q*4+3] * c;
        reinterpret_cast<float4*>(rp)[q] = o;
    }
    #pragma unroll
    for (int g = 0; g < 4; ++g) {
        int u = g * 4;
        float t0 = xs[u+0] * w[16+u+0] * c, t1 = xs[u+1] * w[16+u+1] * c;
        float t2 = xs[u+2] * w[16+u+2] * c, t3 = xs[u+3] * w[16+u+3] * c;
        float4 v0, v1, v2;
        v0.x = t0*ea.y; v0.y = t0*ea.z; v0.z = t0*ea.w; v0.w = t1*ea.y;
        v1.x = t1*ea.z; v1.y = t1*ea.w; v1.z = t2*ea.y; v1.w = t2*ea.z;
        v2.x = t2*ea.w; v2.y = t3*ea.y; v2.z = t3*ea.z; v2.w = t3*ea.w;
        float4* pv = reinterpret_cast<float4*>(rp + 16 + u * 3);
        pv[0] = v0; pv[1] = v1; pv[2] = v2;
    }
}

// ---------------- e2: MFMA edge pass 2 ----------------
#define E2_W1T 0
#define E2_W2T 8192
#define E2_H   (8192 + 6144)
__global__ __launch_bounds__(256) void e2_mfma(
    const unsigned* __restrict__ elep, const float4* __restrict__ eatp,
    const int* __restrict__ esrcp,
    const float* __restrict__ fc2_W1, const float* __restrict__ fc2_W2,
    const float* __restrict__ h0, const float* __restrict__ hv,
    float* __restrict__ ef, int base, int len)
{
    __shared__ __align__(16) unsigned char lds[8192 + 6144 + 32768];
    stage_w1t(fc2_W1, lds, E2_W1T, 64);
    stage_w2t(fc2_W2, lds, E2_W2T, 48);

    int tid = threadIdx.x;
    int i = blockIdx.x * 256 + tid;
    int lane = tid & 63, wv = tid >> 6;
    int kk = lane >> 4, l15 = lane & 15;

    unsigned ep[5];
    if (i < len) {
        const unsigned* pe = elep + (size_t)(base + i) * 5;
        #pragma unroll
        for (int q = 0; q < 5; ++q) ep[q] = pe[q];
    } else {
        #pragma unroll
        for (int q = 0; q < 5; ++q) ep[q] = 0u;
    }
    __syncthreads();

    // ---- layer 1 ----
    #pragma unroll
    for (int mt = 0; mt < 4; ++mt) {
        int sl = mt * 16 + l15;
        int v0 = __shfl((int)ep[0], sl, 64);
        int v1 = __shfl((int)ep[1], sl, 64);
        int v2 = __shfl((int)ep[2], sl, 64);
        int v3 = __shfl((int)ep[3], sl, 64);
        int v4 = __shfl((int)ep[4], sl, 64);
        union { int u[4]; bf16x8 v; } au;
        au.u[0] = (kk == 0) ? v0 : ((kk == 1) ? v4 : 0);
        au.u[1] = (kk == 0) ? v1 : 0;
        au.u[2] = (kk == 0) ? v2 : 0;
        au.u[3] = (kk == 0) ? v3 : 0;
        bf16x8 afrag = au.v;
        #pragma unroll
        for (int nt = 0; nt < 4; ++nt) {
            int r = nt * 16 + l15;
            bf16x8 bfrag = *reinterpret_cast<const bf16x8*>(
                lds + E2_W1T + r * 128 + ((kk ^ (r & 7)) << 4));
            f32x4 acc = {0.f, 0.f, 0.f, 0.f};
            acc = __builtin_amdgcn_mfma_f32_16x16x32_bf16(afrag, bfrag, acc, 0, 0, 0);
            #pragma unroll
            for (int r4 = 0; r4 < 4; ++r4) {
                int row = wv * 64 + mt * 16 + kk * 4 + r4;
                int col = nt * 16 + l15;
                int addr = E2_H + row * 128 + ((((col >> 3) ^ (row & 7))) << 4) + ((col & 7) << 1);
                *reinterpret_cast<unsigned short*>(lds + addr) = cvt_bf16(silu_f(acc[r4]));
            }
        }
    }
    __syncthreads();

    // ---- layer 2 (N=48) ----
    f32x4 acc2[4][3];
    #pragma unroll
    for (int mt = 0; mt < 4; ++mt)
        #pragma unroll
        for (int nt = 0; nt < 3; ++nt) acc2[mt][nt] = (f32x4){0.f, 0.f, 0.f, 0.f};

    #pragma unroll
    for (int ks = 0; ks < 2; ++ks) {
        int slot = ks * 4 + kk;
        bf16x8 bfr[3];
        #pragma unroll
        for (int nt = 0; nt < 3; ++nt) {
            int r = nt * 16 + l15;
            bfr[nt] = *reinterpret_cast<const bf16x8*>(
                lds + E2_W2T + r * 128 + ((slot ^ (r & 7)) << 4));
        }
        #pragma unroll
        for (int mt = 0; mt < 4; ++mt) {
            int row = wv * 64 + mt * 16 + l15;
            bf16x8 a = *reinterpret_cast<const bf16x8*>(
                lds + E2_H + row * 128 + ((slot ^ (row & 7)) << 4));
            #pragma unroll
            for (int nt = 0; nt < 3; ++nt)
                acc2[mt][nt] = __builtin_amdgcn_mfma_f32_16x16x32_bf16(a, bfr[nt], acc2[mt][nt], 0, 0, 0);
        }
    }
    __syncthreads();

    #pragma unroll
    for (int mt = 0; mt < 4; ++mt)
        #pragma unroll
        for (int nt = 0; nt < 3; ++nt)
            #pragma unroll
            for (int r4 = 0; r4 < 4; ++r4) {
                int row = wv * 64 + mt * 16 + kk * 4 + r4;
                int col = nt * 16 + l15;
                int addr = E2_H + row * 128 + ((((col >> 3) ^ (row & 7))) << 4) + ((col & 7) << 1);
                *reinterpret_cast<unsigned short*>(lds + addr) = cvt_bf16(acc2[mt][nt][r4]);
            }
    __syncthreads();

    // ---- epilogue ----
    if (i >= len) return;
    float w[48];
    #pragma unroll
    for (int s6 = 0; s6 < 6; ++s6) {
        uint4 t4 = *reinterpret_cast<const uint4*>(
            lds + E2_H + tid * 128 + ((s6 ^ (tid & 7)) << 4));
        w[s6*8+0] = blo(t4.x); w[s6*8+1] = bhi(t4.x);
        w[s6*8+2] = blo(t4.y); w[s6*8+3] = bhi(t4.y);
        w[s6*8+4] = blo(t4.z); w[s6*8+5] = bhi(t4.z);
        w[s6*8+6] = blo(t4.w); w[s6*8+7] = bhi(t4.w);
    }
    int s = esrcp[base + i];
    float4 ea = eatp[base + i];
    const float c = 0.125f * 0.25f;
    float* rp = ef + (size_t)i * 48;

    {
        const float4* ph = reinterpret_cast<const float4*>(h0 + (size_t)s * 32);
        #pragma unroll
        for (int q = 0; q < 8; ++q) {
            float4 g = ph[q];
            float4 o;
            o.x = g.x * ea.x * w[q*4+0] * c;
            o.y = g.y * ea.x * w[q*4+1] * c;
            o.z = g.z * ea.x * w[q*4+2] * c;
            o.w = g.w * ea.x * w[q*4+3] * c;
            reinterpret_cast<float4*>(rp)[q] = o;
        }
    }
    {
        float dv[16];
        #pragma unroll
        for (int u = 0; u < 16; ++u) dv[u] = 0.f;
        const float4* pv = reinterpret_cast<const float4*>(hv + (size_t)s * 48);
        #pragma unroll
        for (int q = 0; q < 12; ++q) {
            float4 v = pv[q];
            #pragma unroll
            for (int z = 0; z < 4; ++z) {
                int pos = q*4 + z;
                float wt = (pos%3==0) ? ea.y : ((pos%3==1) ? ea.z : ea.w);
                float val = (z==0) ? v.x : (z==1) ? v.y : (z==2) ? v.z : v.w;
                dv[pos/3] += val * wt;
            }
        }
        const float c2 = c * INV_SQRT3;
        #pragma unroll
        for (int q = 0; q < 4; ++q) {
            float4 o;
            o.x = dv[q*4+0] * w[32+q*4+0] * c2;
            o.y = dv[q*4+1] * w[32+q*4+1] * c2;
            o.z = dv[q*4+2] * w[32+q*4+2] * c2;
            o.w = dv[q*4+3] * w[32+q*4+3] * c2;
            reinterpret_cast<float4*>(rp)[8+q] = o;
        }
    }
}

// ---------------- g1: wave-per-node contiguous row-sum (64 ch) ----------------
__global__ __launch_bounds__(256) void g1_gather(
    const int* __restrict__ offs, const int* __restrict__ cnt,
    const float* __restrict__ ef,
    int base, int len, float* __restrict__ mid)
{
    int gw = blockIdx.x * 4 + (threadIdx.x >> 6);
    int lane = threadIdx.x & 63;
    if (gw >= NN) return;
    int lo = offs[gw], deg = cnt[gw];
    int sub = lane >> 4;
    int ch4 = lane & 15;

    float4 acc; acc.x = 0.f; acc.y = 0.f; acc.z = 0.f; acc.w = 0.f;
    for (int t = 0; t < deg; t += 4) {
        int idx = t + sub;
        if (idx < deg) {
            unsigned r = (unsigned)(lo + idx - base);
            if (r < (unsigned)len) {
                float4 v = reinterpret_cast<const float4*>(ef + (size_t)r * 64)[ch4];
                acc.x += v.x; acc.y += v.y; acc.z += v.z; acc.w += v.w;
            }
        }
    }
    acc.x += __shfl_xor(acc.x, 16, 64); acc.y += __shfl_xor(acc.y, 16, 64);
    acc.z += __shfl_xor(acc.z, 16, 64); acc.w += __shfl_xor(acc.w, 16, 64);
    acc.x += __shfl_xor(acc.x, 32, 64); acc.y += __shfl_xor(acc.y, 32, 64);
    acc.z += __shfl_xor(acc.z, 32, 64); acc.w += __shfl_xor(acc.w, 32, 64);

    if (lane < 16) {
        float4* mp = reinterpret_cast<float4*>(mid + (size_t)gw * 64);
        float4 v = mp[lane];
        v.x += acc.x; v.y += acc.y; v.z += acc.z; v.w += acc.w;
        mp[lane] = v;
    }
}

// ---------------- kernel 3: node mid (gates, h0, hv, s2) ----------------
__global__ __launch_bounds__(256) void k3_nodes(
    const float* __restrict__ node_attr, const float* __restrict__ ssc,
    const float* __restrict__ mid,
    const float* __restrict__ W_l2s, const float* __restrict__ W_l2v,
    const float* __restrict__ W_sc2, const float* __restrict__ W12s,
    const float* __restrict__ W12v,
    float* __restrict__ h0, float* __restrict__ hv, float* __restrict__ s2)
{
    int n = blockIdx.x * 256 + threadIdx.x;
    if (n >= NN) return;

    float na = node_attr[n];
    float m[64];
    {
        const float4* p = reinterpret_cast<const float4*>(mid + (size_t)n * 64);
        #pragma unroll
        for (int q = 0; q < 16; ++q) {
            float4 v = p[q];
            m[q*4+0] = v.x; m[q*4+1] = v.y; m[q*4+2] = v.z; m[q*4+3] = v.w;
        }
    }

    float scal[32], gates[16];
    const float4* pss = reinterpret_cast<const float4*>(ssc + (size_t)n * 48);
    #pragma unroll
    for (int jb = 0; jb < 12; ++jb) {
        float a0 = 0.f, a1 = 0.f, a2 = 0.f, a3 = 0.f;
        #pragma unroll
        for (int u = 0; u < 16; ++u) {
            float x = m[u]; const float* w = W_l2s + u * 48 + jb * 4;
            a0 += x * w[0]; a1 += x * w[1]; a2 += x * w[2]; a3 += x * w[3];
        }
        float4 sv = pss[jb];
        float cc = 0.25f * na;
        float g0 = C_S * sv.x + C_X * a0 * cc;
        float g1 = C_S * sv.y + C_X * a1 * cc;
        float g2 = C_S * sv.z + C_X * a2 * cc;
        float g3 = C_S * sv.w + C_X * a3 * cc;
        if (jb < 8) {
            int j = jb * 4;
            scal[j+0] = silu_f(g0); scal[j+1] = silu_f(g1);
            scal[j+2] = silu_f(g2); scal[j+3] = silu_f(g3);
        } else {
            int j = jb * 4 - 32;
            gates[j+0] = sigm_f(g0); gates[j+1] = sigm_f(g1);
            gates[j+2] = sigm_f(g2); gates[j+3] = sigm_f(g3);
        }
    }

    float vec[48];
    #pragma unroll
    for (int w = 0; w < 16; ++w) {
        float a0 = 0.f, a1 = 0.f, a2 = 0.f;
        #pragma unroll
        for (int u = 0; u < 16; ++u) {
            float wt = W_l2v[u * 16 + w];
            a0 += m[16 + u*3 + 0] * wt;
            a1 += m[16 + u*3 + 1] * wt;
            a2 += m[16 + u*3 + 2] * wt;
        }
        float gt = gates[w] * 0.25f * na;
        vec[w*3+0] = a0 * gt; vec[w*3+1] = a1 * gt; vec[w*3+2] = a2 * gt;
    }

    {
        float acc = 0.f;
        #pragma unroll
        for (int j = 0; j < 32; ++j) acc += scal[j] * W_sc2[j];
        s2[n] = acc * INV_SQRT32 * na;
    }

    {
        float c2 = INV_SQRT32 * na;
        float4* ph = reinterpret_cast<float4*>(h0 + (size_t)n * 32);
        #pragma unroll
        for (int jb = 0; jb < 8; ++jb) {
            float a0 = 0.f, a1 = 0.f, a2 = 0.f, a3 = 0.f;
            #pragma unroll
            for (int k = 0; k < 32; ++k) {
                float x = scal[k]; const float* w = W12s + k * 32 + jb * 4;
                a0 += x * w[0]; a1 += x * w[1]; a2 += x * w[2]; a3 += x * w[3];
            }
            float4 o; o.x = a0 * c2; o.y = a1 * c2; o.z = a2 * c2; o.w = a3 * c2;
            ph[jb] = o;
        }
    }

    {
        float c3 = 0.25f * na;
        float hvv[48];
        #pragma unroll
        for (int w = 0; w < 16; ++w) {
            float a0 = 0.f, a1 = 0.f, a2 = 0.f;
            #pragma unroll
            for (int u = 0; u < 16; ++u) {
                float wt = W12v[u * 16 + w];
                a0 += vec[u*3+0] * wt; a1 += vec[u*3+1] * wt; a2 += vec[u*3+2] * wt;
            }
            hvv[w*3+0] = a0 * c3; hvv[w*3+1] = a1 * c3; hvv[w*3+2] = a2 * c3;
        }
        float4* ph = reinterpret_cast<float4*>(hv + (size_t)n * 48);
        #pragma unroll
        for (int q = 0; q < 12; ++q) {
            float4 o; o.x = hvv[q*4+0]; o.y = hvv[q*4+1]; o.z = hvv[q*4+2]; o.w = hvv[q*4+3];
            ph[q] = o;
        }
    }
}

// ---------------- g2: wave-per-node contiguous row-sum (48 ch) ----------------
__global__ __launch_bounds__(256) void g2_gather(
    const int* __restrict__ offs, const int* __restrict__ cnt,
    const float* __restrict__ ef,
    int base, int len, float* __restrict__ mid2)
{
    int gw = blockIdx.x * 4 + (threadIdx.x >> 6);
    int lane = threadIdx.x & 63;
    if (gw >= NN) return;
    int lo = offs[gw], deg = cnt[gw];
    int sub = lane >> 4;
    int ch4 = lane & 15;

    float4 acc; acc.x = 0.f; acc.y = 0.f; acc.z = 0.f; acc.w = 0.f;
    for (int t = 0; t < deg; t += 4) {
        int idx = t + sub;
        if (idx < deg && ch4 < 12) {
            unsigned r = (unsigned)(lo + idx - base);
            if (r < (unsigned)len) {
                float4 v = reinterpret_cast<const float4*>(ef + (size_t)r * 48)[ch4];
                acc.x += v.x; acc.y += v.y; acc.z += v.z; acc.w += v.w;
            }
        }
    }
    acc.x += __shfl_xor(acc.x, 16, 64); acc.y += __shfl_xor(acc.y, 16, 64);
    acc.z += __shfl_xor(acc.z, 16, 64); acc.w += __shfl_xor(acc.w, 16, 64);
    acc.x += __shfl_xor(acc.x, 32, 64); acc.y += __shfl_xor(acc.y, 32, 64);
    acc.z += __shfl_xor(acc.z, 32, 64); acc.w += __shfl_xor(acc.w, 32, 64);

    if (lane < 12) {
        float4* mp = reinterpret_cast<float4*>(mid2 + (size_t)gw * 48);
        float4 v = mp[lane];
        v.x += acc.x; v.y += acc.y; v.z += acc.z; v.w += acc.w;
        mp[lane] = v;
    }
}

// ---------------- kernel 5: node final ----------------
__global__ __launch_bounds__(256) void k5_nodes(
    const float* __restrict__ node_attr, const float* __restrict__ mid2,
    const float* __restrict__ W_lin2_2, const float* __restrict__ s2,
    float* __restrict__ out)
{
    int n = blockIdx.x * 256 + threadIdx.x;
    if (n >= NN) return;
    float acc = 0.f;
    const float4* p = reinterpret_cast<const float4*>(mid2 + (size_t)n * 48);
    #pragma unroll
    for (int q = 0; q < 12; ++q) {
        float4 v = p[q];
        acc += v.x * W_lin2_2[q*4+0] + v.y * W_lin2_2[q*4+1]
             + v.z * W_lin2_2[q*4+2] + v.w * W_lin2_2[q*4+3];
    }
    out[n] = C_S * s2[n] + C_X * acc * INV_SQRT48 * node_attr[n];
}

extern "C" void kernel_launch(void* const* d_in, const int* in_sizes, int n_in,
                              void* d_out, int out_size, void* d_ws, size_t ws_size,
                              hipStream_t stream)
{
    const float* node_input = (const float*)d_in[0];
    const float* node_attr  = (const float*)d_in[1];
    const float* edge_attr  = (const float*)d_in[2];
    const float* ele        = (const float*)d_in[3];
    const float* W_sc1      = (const float*)d_in[4];
    const float* W_lin1_1   = (const float*)d_in[5];
    const float* fc1_W1     = (const float*)d_in[6];
    const float* fc1_W2     = (const float*)d_in[7];
    const float* W_l2s_1    = (const float*)d_in[8];
    const float* W_l2v_1    = (const float*)d_in[9];
    const float* W_sc2      = (const float*)d_in[10];
    const float* W_lin1_2s  = (const float*)d_in[11];
    const float* W_lin1_2v  = (const float*)d_in[12];
    const float* fc2_W1     = (const float*)d_in[13];
    const float* fc2_W2     = (const float*)d_in[14];
    const float* W_lin2_2   = (const float*)d_in[15];
    const int*   esrc       = (const int*)d_in[16];
    const int*   edst       = (const int*)d_in[17];
    float* out = (float*)d_out;
    float* wsf = (float*)d_ws;

    float*    x1     = wsf + OFF_X1;
    float*    ssc    = wsf + OFF_SS;
    float*    mid    = wsf + OFF_MID;    // 64N; later reused as mid2 (48N)
    float*    mid2   = wsf + OFF_MID;
    float*    h0     = wsf + OFF_H0;
    float*    hv     = wsf + OFF_HV;
    float*    s2     = wsf + OFF_S2;
    int*      cnt    = (int*)(wsf + OFF_CNT);
    int*      offs   = (int*)(wsf + OFF_OFFS);
    int*      cursor = (int*)(wsf + OFF_CUR);
    int*      part   = (int*)(wsf + OFF_PART);
    int*      sorted = (int*)(wsf + OFF_SORT);
    unsigned* elep   = (unsigned*)(wsf + OFF_ELEP);
    float4*   eatp   = (float4*)(wsf + OFF_EATP);
    int*      esrcp  = (int*)(wsf + OFF_ESRCP);
    float*    ef     = wsf + OFF_EF;

    size_t total_f = ws_size / 4;
    size_t avail = (total_f > OFF_EF) ? (total_f - OFF_EF) : 0;
    long long C1 = (long long)(avail / 64); if (C1 > NE) C1 = NE; if (C1 < 1) C1 = 1;
    long long C2 = (long long)(avail / 48); if (C2 > NE) C2 = NE; if (C2 < 1) C2 = 1;

    dim3 blk(256);
    int nodeGrid = (NN + 255) / 256;
    int edgeGrid = (NE + 255) / 256;
    int waveGrid = (NN + 3) / 4;

    hipMemsetAsync(cnt, 0, (size_t)NN * sizeof(int), stream);
    hipMemsetAsync(mid, 0, (size_t)NN * 64 * sizeof(float), stream);

    // CSR build + permute
    hist_k<<<edgeGrid, blk, 0, stream>>>(edst, cnt);
    s1_partial<<<NSCAN, SCAN_B, 0, stream>>>(cnt, part);
    s2_scan<<<1, 1, 0, stream>>>(part);
    s3_offsets<<<NSCAN, SCAN_B, 0, stream>>>(cnt, part, offs, cursor);
    fill_k<<<edgeGrid, blk, 0, stream>>>(edst, cursor, sorted);
    permute_k<<<edgeGrid, blk, 0, stream>>>(sorted, ele, edge_attr, esrc,
                                            elep, eatp, esrcp);

    // node pre
    k1_nodes<<<nodeGrid, blk, 0, stream>>>(node_input, node_attr, W_sc1, W_lin1_1, x1, ssc);

    // pass 1
    for (long long b = 0; b < NE; b += C1) {
        int len = (int)((NE - b < C1) ? (NE - b) : C1);
        e1_mfma<<<(len + 255) / 256, blk, 0, stream>>>(elep, eatp, esrcp,
                                                       fc1_W1, fc1_W2, x1,
                                                       ef, (int)b, len);
        g1_gather<<<waveGrid, blk, 0, stream>>>(offs, cnt, ef, (int)b, len, mid);
    }

    // node mid
    k3_nodes<<<nodeGrid, blk, 0, stream>>>(node_attr, ssc, mid, W_l2s_1, W_l2v_1, W_sc2,
                                           W_lin1_2s, W_lin1_2v, h0, hv, s2);

    hipMemsetAsync(mid2, 0, (size_t)NN * 48 * sizeof(float), stream);

    // pass 2
    for (long long b = 0; b < NE; b += C2) {
        int len = (int)((NE - b < C2) ? (NE - b) : C2);
        e2_mfma<<<(len + 255) / 256, blk, 0, stream>>>(elep, eatp, esrcp,
                                                       fc2_W1, fc2_W2, h0, hv,
                                                       ef, (int)b, len);
        g2_gather<<<waveGrid, blk, 0, stream>>>(offs, cnt, ef, (int)b, len, mid2);
    }

    // final
    k5_nodes<<<nodeGrid, blk, 0, stream>>>(node_attr, mid2, W_lin2_2, s2, out);
}

// Round 8
// 1005.686 us; speedup vs baseline: 9.4860x; 1.3685x over previous
//
#include <hip/hip_runtime.h>
#include <math.h>

#define NN 100000
#define NE 1600000

typedef __attribute__((ext_vector_type(8))) short bf16x8;
typedef __attribute__((ext_vector_type(4))) float f32x4;

// ---- workspace layout (element offsets; all 4-byte elems) ----
#define OFF_X1    ((size_t)0)                    // N*16 f
#define OFF_SS    ((size_t)NN * 16)              // N*48 f
#define OFF_MID   ((size_t)NN * 64)              // N*64 f (then N*48 mid2)
#define OFF_H0    ((size_t)NN * 128)             // N*32 f
#define OFF_HV    ((size_t)NN * 160)             // N*48 f
#define OFF_S2    ((size_t)NN * 208)             // N    f
#define OFF_CNT   ((size_t)NN * 209)             // N    i
#define OFF_OFFS  ((size_t)NN * 210)             // N    i
#define OFF_PART  ((size_t)NN * 211)             // 128  i
#define OFF_SLOTL (OFF_PART + 128)               // E    i
#define OFF_SLOT  (OFF_SLOTL + (size_t)NE)       // E    i
#define OFF_EF    (OFF_SLOT + (size_t)NE)        // edge rows, bf16-packed (adaptive)

#define INV_SQRT10 0.31622776601683794f
#define INV_SQRT3  0.57735026918962576f
#define INV_SQRT32 0.17677669529663687f
#define INV_SQRT48 0.14433756729740643f
#define C_S 0.3826834323650898f
#define C_X 0.9238795325112867f

#define SCAN_B 1024
#define NSCAN ((NN + SCAN_B - 1) / SCAN_B)

__device__ __forceinline__ float silu_f(float x) { return x / (1.f + __expf(-x)); }
__device__ __forceinline__ float sigm_f(float x) { return 1.f / (1.f + __expf(-x)); }

__device__ __forceinline__ unsigned short cvt_bf16(float a) {
    unsigned u = __float_as_uint(a);
    u = (u + 0x7fffu + ((u >> 16) & 1u)) >> 16;
    return (unsigned short)u;
}
__device__ __forceinline__ unsigned cvt2_bf16(float a, float b) {
    return (unsigned)cvt_bf16(a) | ((unsigned)cvt_bf16(b) << 16);
}
__device__ __forceinline__ float blo(unsigned u) { return __uint_as_float(u << 16); }
__device__ __forceinline__ float bhi(unsigned u) { return __uint_as_float(u & 0xffff0000u); }

// ---------------- CSR: rank (single atomic pass; cnt -> degrees) ----------------
__global__ __launch_bounds__(256) void rank_k(const int* __restrict__ edst,
                                              int* __restrict__ cnt,
                                              int* __restrict__ slotl)
{
    int e = blockIdx.x * 256 + threadIdx.x;
    if (e >= NE) return;
    slotl[e] = atomicAdd(&cnt[edst[e]], 1);
}

__global__ __launch_bounds__(SCAN_B) void s1_partial(const int* __restrict__ cnt,
                                                     int* __restrict__ part)
{
    __shared__ int sm[SCAN_B];
    int i = blockIdx.x * SCAN_B + threadIdx.x;
    sm[threadIdx.x] = (i < NN) ? cnt[i] : 0;
    __syncthreads();
    #pragma unroll
    for (int s = SCAN_B / 2; s > 0; s >>= 1) {
        if (threadIdx.x < s) sm[threadIdx.x] += sm[threadIdx.x + s];
        __syncthreads();
    }
    if (threadIdx.x == 0) part[blockIdx.x] = sm[0];
}

__global__ void s2_scan(int* __restrict__ part)
{
    if (threadIdx.x == 0 && blockIdx.x == 0) {
        int acc = 0;
        for (int b = 0; b < NSCAN; ++b) { int v = part[b]; part[b] = acc; acc += v; }
    }
}

__global__ __launch_bounds__(SCAN_B) void s3_offsets(const int* __restrict__ cnt,
                                                     const int* __restrict__ part,
                                                     int* __restrict__ offs)
{
    __shared__ int sm[SCAN_B];
    int i = blockIdx.x * SCAN_B + threadIdx.x;
    int v = (i < NN) ? cnt[i] : 0;
    sm[threadIdx.x] = v;
    __syncthreads();
    #pragma unroll
    for (int s = 1; s < SCAN_B; s <<= 1) {
        int t = (threadIdx.x >= s) ? sm[threadIdx.x - s] : 0;
        __syncthreads();
        sm[threadIdx.x] += t;
        __syncthreads();
    }
    if (i < NN) offs[i] = sm[threadIdx.x] - v + part[blockIdx.x];
}

// ---------------- slot: CSR position per edge (no atomics) ----------------
__global__ __launch_bounds__(256) void slot_k(const int* __restrict__ edst,
                                              const int* __restrict__ slotl,
                                              const int* __restrict__ offs,
                                              int* __restrict__ slot)
{
    int e = blockIdx.x * 256 + threadIdx.x;
    if (e >= NE) return;
    slot[e] = offs[edst[e]] + slotl[e];
}

// ---------------- kernel 1: node pre (s_scal, x1) ----------------
__global__ __launch_bounds__(256) void k1_nodes(
    const float* __restrict__ node_input, const float* __restrict__ node_attr,
    const float* __restrict__ W_sc1, const float* __restrict__ W_lin1_1,
    float* __restrict__ x1, float* __restrict__ ssc)
{
    int n = blockIdx.x * 256 + threadIdx.x;
    if (n >= NN) return;

    float ni[16];
    {
        const float4* p = reinterpret_cast<const float4*>(node_input + (size_t)n * 16);
        #pragma unroll
        for (int q = 0; q < 4; ++q) {
            float4 v = p[q];
            ni[q*4+0] = v.x; ni[q*4+1] = v.y; ni[q*4+2] = v.z; ni[q*4+3] = v.w;
        }
    }
    float sc = 0.25f * node_attr[n];

    float4* po = reinterpret_cast<float4*>(ssc + (size_t)n * 48);
    #pragma unroll
    for (int jb = 0; jb < 12; ++jb) {
        float a0 = 0.f, a1 = 0.f, a2 = 0.f, a3 = 0.f;
        #pragma unroll
        for (int u = 0; u < 16; ++u) {
            float x = ni[u]; const float* w = W_sc1 + u * 48 + jb * 4;
            a0 += x * w[0]; a1 += x * w[1]; a2 += x * w[2]; a3 += x * w[3];
        }
        float4 o; o.x = a0 * sc; o.y = a1 * sc; o.z = a2 * sc; o.w = a3 * sc;
        po[jb] = o;
    }
    float4* px = reinterpret_cast<float4*>(x1 + (size_t)n * 16);
    #pragma unroll
    for (int jb = 0; jb < 4; ++jb) {
        float a0 = 0.f, a1 = 0.f, a2 = 0.f, a3 = 0.f;
        #pragma unroll
        for (int u = 0; u < 16; ++u) {
            float x = ni[u]; const float* w = W_lin1_1 + u * 16 + jb * 4;
            a0 += x * w[0]; a1 += x * w[1]; a2 += x * w[2]; a3 += x * w[3];
        }
        float4 o; o.x = a0 * sc; o.y = a1 * sc; o.z = a2 * sc; o.w = a3 * sc;
        px[jb] = o;
    }
}

// ================= MFMA edge kernels =================
// LDS swizzled 16B slots: phys_slot = slot ^ (row & 7)

__device__ __forceinline__ void stage_w1t(const float* __restrict__ W1,
                                          unsigned char* lds, int W1T_OFF, int ncols)
{
    for (int idx = threadIdx.x; idx < ncols * 32; idx += 256) {
        int r = idx >> 5, k = idx & 31;
        float v = (k < 10) ? W1[k * ncols + r] : 0.f;
        int addr = W1T_OFF + r * 128 + (((k >> 3) ^ (r & 7)) << 4) + ((k & 7) << 1);
        *reinterpret_cast<unsigned short*>(lds + addr) = cvt_bf16(v);
    }
}

__device__ __forceinline__ void stage_w2t(const float* __restrict__ W2,
                                          unsigned char* lds, int W2T_OFF, int ncols)
{
    for (int idx = threadIdx.x; idx < ncols * 64; idx += 256) {
        int r = idx >> 6, k = idx & 63;
        float v = W2[k * ncols + r];
        int addr = W2T_OFF + r * 128 + (((k >> 3) ^ (r & 7)) << 4) + ((k & 7) << 1);
        *reinterpret_cast<unsigned short*>(lds + addr) = cvt_bf16(v);
    }
}

// ---------------- e1: MFMA edge pass 1 (raw edge order, slot-scatter) ----------------
#define E1_W1T 0
#define E1_W2T 8192
#define E1_H   (8192 + 4096)
__global__ __launch_bounds__(256) void e1_mfma(
    const float* __restrict__ ele, const float* __restrict__ eattr,
    const int* __restrict__ esrc, const int* __restrict__ slot,
    const float* __restrict__ fc1_W1, const float* __restrict__ fc1_W2,
    const float* __restrict__ x1,
    unsigned* __restrict__ ef, int base, int len)
{
    __shared__ __align__(16) unsigned char lds[8192 + 4096 + 32768];
    stage_w1t(fc1_W1, lds, E1_W1T, 64);
    stage_w2t(fc1_W2, lds, E1_W2T, 32);

    int tid = threadIdx.x;
    int i = blockIdx.x * 256 + tid;       // global edge id
    int lane = tid & 63, wv = tid >> 6;
    int kk = lane >> 4, l15 = lane & 15;

    unsigned ep[5];
    if (i < NE) {
        const float2* pe = reinterpret_cast<const float2*>(ele + (size_t)i * 10);
        #pragma unroll
        for (int q = 0; q < 5; ++q) {
            float2 v = pe[q];
            ep[q] = cvt2_bf16(v.x * INV_SQRT10, v.y * INV_SQRT10);
        }
    } else {
        #pragma unroll
        for (int q = 0; q < 5; ++q) ep[q] = 0u;
    }
    __syncthreads();

    // ---- layer 1: h = silu(el @ W1) -> bf16 H ----
    #pragma unroll
    for (int mt = 0; mt < 4; ++mt) {
        int sl = mt * 16 + l15;
        int v0 = __shfl((int)ep[0], sl, 64);
        int v1 = __shfl((int)ep[1], sl, 64);
        int v2 = __shfl((int)ep[2], sl, 64);
        int v3 = __shfl((int)ep[3], sl, 64);
        int v4 = __shfl((int)ep[4], sl, 64);
        union { int u[4]; bf16x8 v; } au;
        au.u[0] = (kk == 0) ? v0 : ((kk == 1) ? v4 : 0);
        au.u[1] = (kk == 0) ? v1 : 0;
        au.u[2] = (kk == 0) ? v2 : 0;
        au.u[3] = (kk == 0) ? v3 : 0;
        bf16x8 afrag = au.v;
        #pragma unroll
        for (int nt = 0; nt < 4; ++nt) {
            int r = nt * 16 + l15;
            bf16x8 bfrag = *reinterpret_cast<const bf16x8*>(
                lds + E1_W1T + r * 128 + ((kk ^ (r & 7)) << 4));
            f32x4 acc = {0.f, 0.f, 0.f, 0.f};
            acc = __builtin_amdgcn_mfma_f32_16x16x32_bf16(afrag, bfrag, acc, 0, 0, 0);
            #pragma unroll
            for (int r4 = 0; r4 < 4; ++r4) {
                int row = wv * 64 + mt * 16 + kk * 4 + r4;
                int col = nt * 16 + l15;
                int addr = E1_H + row * 128 + ((((col >> 3) ^ (row & 7))) << 4) + ((col & 7) << 1);
                *reinterpret_cast<unsigned short*>(lds + addr) = cvt_bf16(silu_f(acc[r4]));
            }
        }
    }
    __syncthreads();

    // ---- layer 2: w = H @ W2 (N=32) ----
    f32x4 acc2[4][2];
    #pragma unroll
    for (int mt = 0; mt < 4; ++mt)
        #pragma unroll
        for (int nt = 0; nt < 2; ++nt) acc2[mt][nt] = (f32x4){0.f, 0.f, 0.f, 0.f};

    #pragma unroll
    for (int ks = 0; ks < 2; ++ks) {
        int sslot = ks * 4 + kk;
        bf16x8 bfr[2];
        #pragma unroll
        for (int nt = 0; nt < 2; ++nt) {
            int r = nt * 16 + l15;
            bfr[nt] = *reinterpret_cast<const bf16x8*>(
                lds + E1_W2T + r * 128 + ((sslot ^ (r & 7)) << 4));
        }
        #pragma unroll
        for (int mt = 0; mt < 4; ++mt) {
            int row = wv * 64 + mt * 16 + l15;
            bf16x8 a = *reinterpret_cast<const bf16x8*>(
                lds + E1_H + row * 128 + ((sslot ^ (row & 7)) << 4));
            #pragma unroll
            for (int nt = 0; nt < 2; ++nt)
                acc2[mt][nt] = __builtin_amdgcn_mfma_f32_16x16x32_bf16(a, bfr[nt], acc2[mt][nt], 0, 0, 0);
        }
    }
    __syncthreads();

    #pragma unroll
    for (int mt = 0; mt < 4; ++mt)
        #pragma unroll
        for (int nt = 0; nt < 2; ++nt)
            #pragma unroll
            for (int r4 = 0; r4 < 4; ++r4) {
                int row = wv * 64 + mt * 16 + kk * 4 + r4;
                int col = nt * 16 + l15;
                int addr = E1_H + row * 128 + ((((col >> 3) ^ (row & 7))) << 4) + ((col & 7) << 1);
                *reinterpret_cast<unsigned short*>(lds + addr) = cvt_bf16(acc2[mt][nt][r4]);
            }
    __syncthreads();

    // ---- epilogue: assemble 64-ch row, bf16-pack, scatter to slot ----
    if (i >= NE) return;
    int s_out = slot[i];
    unsigned r_off = (unsigned)(s_out - base);
    if (r_off >= (unsigned)len) return;

    float w[32];
    #pragma unroll
    for (int s6 = 0; s6 < 4; ++s6) {
        uint4 t4 = *reinterpret_cast<const uint4*>(
            lds + E1_H + tid * 128 + ((s6 ^ (tid & 7)) << 4));
        w[s6*8+0] = blo(t4.x); w[s6*8+1] = bhi(t4.x);
        w[s6*8+2] = blo(t4.y); w[s6*8+3] = bhi(t4.y);
        w[s6*8+4] = blo(t4.z); w[s6*8+5] = bhi(t4.z);
        w[s6*8+6] = blo(t4.w); w[s6*8+7] = bhi(t4.w);
    }
    int s = esrc[i];
    float4 ea = reinterpret_cast<const float4*>(eattr)[i];
    float xs[16];
    {
        const float4* p = reinterpret_cast<const float4*>(x1 + (size_t)s * 16);
        #pragma unroll
        for (int q = 0; q < 4; ++q) {
            float4 v = p[q];
            xs[q*4+0] = v.x; xs[q*4+1] = v.y; xs[q*4+2] = v.z; xs[q*4+3] = v.w;
        }
    }
    const float c = 0.125f * 0.25f;
    float f[64];
    #pragma unroll
    for (int j = 0; j < 16; ++j) f[j] = xs[j] * ea.x * w[j] * c;
    #pragma unroll
    for (int u = 0; u < 16; ++u) {
        float t = xs[u] * w[16+u] * c;
        f[16+u*3+0] = t * ea.y; f[16+u*3+1] = t * ea.z; f[16+u*3+2] = t * ea.w;
    }
    unsigned* rp = ef + (size_t)r_off * 32;   // 64 bf16 = 32 u32
    #pragma unroll
    for (int q = 0; q < 8; ++q) {
        uint4 o;
        o.x = cvt2_bf16(f[q*8+0], f[q*8+1]);
        o.y = cvt2_bf16(f[q*8+2], f[q*8+3]);
        o.z = cvt2_bf16(f[q*8+4], f[q*8+5]);
        o.w = cvt2_bf16(f[q*8+6], f[q*8+7]);
        reinterpret_cast<uint4*>(rp)[q] = o;
    }
}

// ---------------- e2: MFMA edge pass 2 ----------------
#define E2_W1T 0
#define E2_W2T 8192
#define E2_H   (8192 + 6144)
__global__ __launch_bounds__(256) void e2_mfma(
    const float* __restrict__ ele, const float* __restrict__ eattr,
    const int* __restrict__ esrc, const int* __restrict__ slot,
    const float* __restrict__ fc2_W1, const float* __restrict__ fc2_W2,
    const float* __restrict__ h0, const float* __restrict__ hv,
    unsigned* __restrict__ ef, int base, int len)
{
    __shared__ __align__(16) unsigned char lds[8192 + 6144 + 32768];
    stage_w1t(fc2_W1, lds, E2_W1T, 64);
    stage_w2t(fc2_W2, lds, E2_W2T, 48);

    int tid = threadIdx.x;
    int i = blockIdx.x * 256 + tid;
    int lane = tid & 63, wv = tid >> 6;
    int kk = lane >> 4, l15 = lane & 15;

    unsigned ep[5];
    if (i < NE) {
        const float2* pe = reinterpret_cast<const float2*>(ele + (size_t)i * 10);
        #pragma unroll
        for (int q = 0; q < 5; ++q) {
            float2 v = pe[q];
            ep[q] = cvt2_bf16(v.x * INV_SQRT10, v.y * INV_SQRT10);
        }
    } else {
        #pragma unroll
        for (int q = 0; q < 5; ++q) ep[q] = 0u;
    }
    __syncthreads();

    #pragma unroll
    for (int mt = 0; mt < 4; ++mt) {
        int sl = mt * 16 + l15;
        int v0 = __shfl((int)ep[0], sl, 64);
        int v1 = __shfl((int)ep[1], sl, 64);
        int v2 = __shfl((int)ep[2], sl, 64);
        int v3 = __shfl((int)ep[3], sl, 64);
        int v4 = __shfl((int)ep[4], sl, 64);
        union { int u[4]; bf16x8 v; } au;
        au.u[0] = (kk == 0) ? v0 : ((kk == 1) ? v4 : 0);
        au.u[1] = (kk == 0) ? v1 : 0;
        au.u[2] = (kk == 0) ? v2 : 0;
        au.u[3] = (kk == 0) ? v3 : 0;
        bf16x8 afrag = au.v;
        #pragma unroll
        for (int nt = 0; nt < 4; ++nt) {
            int r = nt * 16 + l15;
            bf16x8 bfrag = *reinterpret_cast<const bf16x8*>(
                lds + E2_W1T + r * 128 + ((kk ^ (r & 7)) << 4));
            f32x4 acc = {0.f, 0.f, 0.f, 0.f};
            acc = __builtin_amdgcn_mfma_f32_16x16x32_bf16(afrag, bfrag, acc, 0, 0, 0);
            #pragma unroll
            for (int r4 = 0; r4 < 4; ++r4) {
                int row = wv * 64 + mt * 16 + kk * 4 + r4;
                int col = nt * 16 + l15;
                int addr = E2_H + row * 128 + ((((col >> 3) ^ (row & 7))) << 4) + ((col & 7) << 1);
                *reinterpret_cast<unsigned short*>(lds + addr) = cvt_bf16(silu_f(acc[r4]));
            }
        }
    }
    __syncthreads();

    f32x4 acc2[4][3];
    #pragma unroll
    for (int mt = 0; mt < 4; ++mt)
        #pragma unroll
        for (int nt = 0; nt < 3; ++nt) acc2[mt][nt] = (f32x4){0.f, 0.f, 0.f, 0.f};

    #pragma unroll
    for (int ks = 0; ks < 2; ++ks) {
        int sslot = ks * 4 + kk;
        bf16x8 bfr[3];
        #pragma unroll
        for (int nt = 0; nt < 3; ++nt) {
            int r = nt * 16 + l15;
            bfr[nt] = *reinterpret_cast<const bf16x8*>(
                lds + E2_W2T + r * 128 + ((sslot ^ (r & 7)) << 4));
        }
        #pragma unroll
        for (int mt = 0; mt < 4; ++mt) {
            int row = wv * 64 + mt * 16 + l15;
            bf16x8 a = *reinterpret_cast<const bf16x8*>(
                lds + E2_H + row * 128 + ((sslot ^ (row & 7)) << 4));
            #pragma unroll
            for (int nt = 0; nt < 3; ++nt)
                acc2[mt][nt] = __builtin_amdgcn_mfma_f32_16x16x32_bf16(a, bfr[nt], acc2[mt][nt], 0, 0, 0);
        }
    }
    __syncthreads();

    #pragma unroll
    for (int mt = 0; mt < 4; ++mt)
        #pragma unroll
        for (int nt = 0; nt < 3; ++nt)
            #pragma unroll
            for (int r4 = 0; r4 < 4; ++r4) {
                int row = wv * 64 + mt * 16 + kk * 4 + r4;
                int col = nt * 16 + l15;
                int addr = E2_H + row * 128 + ((((col >> 3) ^ (row & 7))) << 4) + ((col & 7) << 1);
                *reinterpret_cast<unsigned short*>(lds + addr) = cvt_bf16(acc2[mt][nt][r4]);
            }
    __syncthreads();

    if (i >= NE) return;
    int s_out = slot[i];
    unsigned r_off = (unsigned)(s_out - base);
    if (r_off >= (unsigned)len) return;

    float w[48];
    #pragma unroll
    for (int s6 = 0; s6 < 6; ++s6) {
        uint4 t4 = *reinterpret_cast<const uint4*>(
            lds + E2_H + tid * 128 + ((s6 ^ (tid & 7)) << 4));
        w[s6*8+0] = blo(t4.x); w[s6*8+1] = bhi(t4.x);
        w[s6*8+2] = blo(t4.y); w[s6*8+3] = bhi(t4.y);
        w[s6*8+4] = blo(t4.z); w[s6*8+5] = bhi(t4.z);
        w[s6*8+6] = blo(t4.w); w[s6*8+7] = bhi(t4.w);
    }
    int s = esrc[i];
    float4 ea = reinterpret_cast<const float4*>(eattr)[i];
    const float c = 0.125f * 0.25f;
    float f[48];
    {
        const float4* ph = reinterpret_cast<const float4*>(h0 + (size_t)s * 32);
        #pragma unroll
        for (int q = 0; q < 8; ++q) {
            float4 g = ph[q];
            f[q*4+0] = g.x * ea.x * w[q*4+0] * c;
            f[q*4+1] = g.y * ea.x * w[q*4+1] * c;
            f[q*4+2] = g.z * ea.x * w[q*4+2] * c;
            f[q*4+3] = g.w * ea.x * w[q*4+3] * c;
        }
    }
    {
        float dv[16];
        #pragma unroll
        for (int u = 0; u < 16; ++u) dv[u] = 0.f;
        const float4* pv = reinterpret_cast<const float4*>(hv + (size_t)s * 48);
        #pragma unroll
        for (int q = 0; q < 12; ++q) {
            float4 v = pv[q];
            #pragma unroll
            for (int z = 0; z < 4; ++z) {
                int pos = q*4 + z;
                float wt = (pos%3==0) ? ea.y : ((pos%3==1) ? ea.z : ea.w);
                float val = (z==0) ? v.x : (z==1) ? v.y : (z==2) ? v.z : v.w;
                dv[pos/3] += val * wt;
            }
        }
        const float c2 = c * INV_SQRT3;
        #pragma unroll
        for (int u = 0; u < 16; ++u) f[32+u] = dv[u] * w[32+u] * c2;
    }
    unsigned* rp = ef + (size_t)r_off * 24;   // 48 bf16 = 24 u32
    #pragma unroll
    for (int q = 0; q < 6; ++q) {
        uint4 o;
        o.x = cvt2_bf16(f[q*8+0], f[q*8+1]);
        o.y = cvt2_bf16(f[q*8+2], f[q*8+3]);
        o.z = cvt2_bf16(f[q*8+4], f[q*8+5]);
        o.w = cvt2_bf16(f[q*8+6], f[q*8+7]);
        reinterpret_cast<uint4*>(rp)[q] = o;
    }
}

// ---------------- g1: wave-per-node, 8 edges/iter, bf16 rows (64 ch) ----------------
__global__ __launch_bounds__(256) void g1_gather(
    const int* __restrict__ offs, const int* __restrict__ cnt,
    const unsigned* __restrict__ ef,
    int base, int len, float* __restrict__ mid)
{
    int gw = blockIdx.x * 4 + (threadIdx.x >> 6);
    int lane = threadIdx.x & 63;
    if (gw >= NN) return;
    int lo = offs[gw], deg = cnt[gw];
    int sub = lane >> 3;       // 8 concurrent edges
    int ch8 = lane & 7;        // uint4 slot (8 bf16 = 8 ch)

    float a0=0.f,a1=0.f,a2=0.f,a3=0.f,a4=0.f,a5=0.f,a6=0.f,a7=0.f;
    for (int t = 0; t < deg; t += 8) {
        int idx = t + sub;
        if (idx < deg) {
            unsigned r = (unsigned)(lo + idx - base);
            if (r < (unsigned)len) {
                uint4 v = reinterpret_cast<const uint4*>(ef + (size_t)r * 32)[ch8];
                a0 += blo(v.x); a1 += bhi(v.x);
                a2 += blo(v.y); a3 += bhi(v.y);
                a4 += blo(v.z); a5 += bhi(v.z);
                a6 += blo(v.w); a7 += bhi(v.w);
            }
        }
    }
    #pragma unroll
    for (int m = 8; m <= 32; m <<= 1) {
        a0 += __shfl_xor(a0, m, 64); a1 += __shfl_xor(a1, m, 64);
        a2 += __shfl_xor(a2, m, 64); a3 += __shfl_xor(a3, m, 64);
        a4 += __shfl_xor(a4, m, 64); a5 += __shfl_xor(a5, m, 64);
        a6 += __shfl_xor(a6, m, 64); a7 += __shfl_xor(a7, m, 64);
    }
    if (lane < 8) {
        float4* mp = reinterpret_cast<float4*>(mid + (size_t)gw * 64 + lane * 8);
        float4 v0 = mp[0], v1 = mp[1];
        v0.x += a0; v0.y += a1; v0.z += a2; v0.w += a3;
        v1.x += a4; v1.y += a5; v1.z += a6; v1.w += a7;
        mp[0] = v0; mp[1] = v1;
    }
}

// ---------------- kernel 3: node mid (gates, h0, hv, s2) ----------------
__global__ __launch_bounds__(256) void k3_nodes(
    const float* __restrict__ node_attr, const float* __restrict__ ssc,
    const float* __restrict__ mid,
    const float* __restrict__ W_l2s, const float* __restrict__ W_l2v,
    const float* __restrict__ W_sc2, const float* __restrict__ W12s,
    const float* __restrict__ W12v,
    float* __restrict__ h0, float* __restrict__ hv, float* __restrict__ s2)
{
    int n = blockIdx.x * 256 + threadIdx.x;
    if (n >= NN) return;

    float na = node_attr[n];
    float m[64];
    {
        const float4* p = reinterpret_cast<const float4*>(mid + (size_t)n * 64);
        #pragma unroll
        for (int q = 0; q < 16; ++q) {
            float4 v = p[q];
            m[q*4+0] = v.x; m[q*4+1] = v.y; m[q*4+2] = v.z; m[q*4+3] = v.w;
        }
    }

    float scal[32], gates[16];
    const float4* pss = reinterpret_cast<const float4*>(ssc + (size_t)n * 48);
    #pragma unroll
    for (int jb = 0; jb < 12; ++jb) {
        float a0 = 0.f, a1 = 0.f, a2 = 0.f, a3 = 0.f;
        #pragma unroll
        for (int u = 0; u < 16; ++u) {
            float x = m[u]; const float* w = W_l2s + u * 48 + jb * 4;
            a0 += x * w[0]; a1 += x * w[1]; a2 += x * w[2]; a3 += x * w[3];
        }
        float4 sv = pss[jb];
        float cc = 0.25f * na;
        float g0 = C_S * sv.x + C_X * a0 * cc;
        float g1 = C_S * sv.y + C_X * a1 * cc;
        float g2 = C_S * sv.z + C_X * a2 * cc;
        float g3 = C_S * sv.w + C_X * a3 * cc;
        if (jb < 8) {
            int j = jb * 4;
            scal[j+0] = silu_f(g0); scal[j+1] = silu_f(g1);
            scal[j+2] = silu_f(g2); scal[j+3] = silu_f(g3);
        } else {
            int j = jb * 4 - 32;
            gates[j+0] = sigm_f(g0); gates[j+1] = sigm_f(g1);
            gates[j+2] = sigm_f(g2); gates[j+3] = sigm_f(g3);
        }
    }

    float vec[48];
    #pragma unroll
    for (int w = 0; w < 16; ++w) {
        float a0 = 0.f, a1 = 0.f, a2 = 0.f;
        #pragma unroll
        for (int u = 0; u < 16; ++u) {
            float wt = W_l2v[u * 16 + w];
            a0 += m[16 + u*3 + 0] * wt;
            a1 += m[16 + u*3 + 1] * wt;
            a2 += m[16 + u*3 + 2] * wt;
        }
        float gt = gates[w] * 0.25f * na;
        vec[w*3+0] = a0 * gt; vec[w*3+1] = a1 * gt; vec[w*3+2] = a2 * gt;
    }

    {
        float acc = 0.f;
        #pragma unroll
        for (int j = 0; j < 32; ++j) acc += scal[j] * W_sc2[j];
        s2[n] = acc * INV_SQRT32 * na;
    }

    {
        float c2 = INV_SQRT32 * na;
        float4* ph = reinterpret_cast<float4*>(h0 + (size_t)n * 32);
        #pragma unroll
        for (int jb = 0; jb < 8; ++jb) {
            float a0 = 0.f, a1 = 0.f, a2 = 0.f, a3 = 0.f;
            #pragma unroll
            for (int k = 0; k < 32; ++k) {
                float x = scal[k]; const float* w = W12s + k * 32 + jb * 4;
                a0 += x * w[0]; a1 += x * w[1]; a2 += x * w[2]; a3 += x * w[3];
            }
            float4 o; o.x = a0 * c2; o.y = a1 * c2; o.z = a2 * c2; o.w = a3 * c2;
            ph[jb] = o;
        }
    }

    {
        float c3 = 0.25f * na;
        float hvv[48];
        #pragma unroll
        for (int w = 0; w < 16; ++w) {
            float a0 = 0.f, a1 = 0.f, a2 = 0.f;
            #pragma unroll
            for (int u = 0; u < 16; ++u) {
                float wt = W12v[u * 16 + w];
                a0 += vec[u*3+0] * wt; a1 += vec[u*3+1] * wt; a2 += vec[u*3+2] * wt;
            }
            hvv[w*3+0] = a0 * c3; hvv[w*3+1] = a1 * c3; hvv[w*3+2] = a2 * c3;
        }
        float4* ph = reinterpret_cast<float4*>(hv + (size_t)n * 48);
        #pragma unroll
        for (int q = 0; q < 12; ++q) {
            float4 o; o.x = hvv[q*4+0]; o.y = hvv[q*4+1]; o.z = hvv[q*4+2]; o.w = hvv[q*4+3];
            ph[q] = o;
        }
    }
}

// ---------------- g2: wave-per-node, 8 edges/iter, bf16 rows (48 ch) ----------------
__global__ __launch_bounds__(256) void g2_gather(
    const int* __restrict__ offs, const int* __restrict__ cnt,
    const unsigned* __restrict__ ef,
    int base, int len, float* __restrict__ mid2)
{
    int gw = blockIdx.x * 4 + (threadIdx.x >> 6);
    int lane = threadIdx.x & 63;
    if (gw >= NN) return;
    int lo = offs[gw], deg = cnt[gw];
    int sub = lane >> 3;
    int ch8 = lane & 7;        // active if < 6

    float a0=0.f,a1=0.f,a2=0.f,a3=0.f,a4=0.f,a5=0.f,a6=0.f,a7=0.f;
    for (int t = 0; t < deg; t += 8) {
        int idx = t + sub;
        if (idx < deg && ch8 < 6) {
            unsigned r = (unsigned)(lo + idx - base);
            if (r < (unsigned)len) {
                uint4 v = reinterpret_cast<const uint4*>(ef + (size_t)r * 24)[ch8];
                a0 += blo(v.x); a1 += bhi(v.x);
                a2 += blo(v.y); a3 += bhi(v.y);
                a4 += blo(v.z); a5 += bhi(v.z);
                a6 += blo(v.w); a7 += bhi(v.w);
            }
        }
    }
    #pragma unroll
    for (int m = 8; m <= 32; m <<= 1) {
        a0 += __shfl_xor(a0, m, 64); a1 += __shfl_xor(a1, m, 64);
        a2 += __shfl_xor(a2, m, 64); a3 += __shfl_xor(a3, m, 64);
        a4 += __shfl_xor(a4, m, 64); a5 += __shfl_xor(a5, m, 64);
        a6 += __shfl_xor(a6, m, 64); a7 += __shfl_xor(a7, m, 64);
    }
    if (lane < 6) {
        float4* mp = reinterpret_cast<float4*>(mid2 + (size_t)gw * 48 + lane * 8);
        float4 v0 = mp[0], v1 = mp[1];
        v0.x += a0; v0.y += a1; v0.z += a2; v0.w += a3;
        v1.x += a4; v1.y += a5; v1.z += a6; v1.w += a7;
        mp[0] = v0; mp[1] = v1;
    }
}

// ---------------- kernel 5: node final ----------------
__global__ __launch_bounds__(256) void k5_nodes(
    const float* __restrict__ node_attr, const float* __restrict__ mid2,
    const float* __restrict__ W_lin2_2, const float* __restrict__ s2,
    float* __restrict__ out)
{
    int n = blockIdx.x * 256 + threadIdx.x;
    if (n >= NN) return;
    float acc = 0.f;
    const float4* p = reinterpret_cast<const float4*>(mid2 + (size_t)n * 48);
    #pragma unroll
    for (int q = 0; q < 12; ++q) {
        float4 v = p[q];
        acc += v.x * W_lin2_2[q*4+0] + v.y * W_lin2_2[q*4+1]
             + v.z * W_lin2_2[q*4+2] + v.w * W_lin2_2[q*4+3];
    }
    out[n] = C_S * s2[n] + C_X * acc * INV_SQRT48 * node_attr[n];
}

extern "C" void kernel_launch(void* const* d_in, const int* in_sizes, int n_in,
                              void* d_out, int out_size, void* d_ws, size_t ws_size,
                              hipStream_t stream)
{
    const float* node_input = (const float*)d_in[0];
    const float* node_attr  = (const float*)d_in[1];
    const float* edge_attr  = (const float*)d_in[2];
    const float* ele        = (const float*)d_in[3];
    const float* W_sc1      = (const float*)d_in[4];
    const float* W_lin1_1   = (const float*)d_in[5];
    const float* fc1_W1     = (const float*)d_in[6];
    const float* fc1_W2     = (const float*)d_in[7];
    const float* W_l2s_1    = (const float*)d_in[8];
    const float* W_l2v_1    = (const float*)d_in[9];
    const float* W_sc2      = (const float*)d_in[10];
    const float* W_lin1_2s  = (const float*)d_in[11];
    const float* W_lin1_2v  = (const float*)d_in[12];
    const float* fc2_W1     = (const float*)d_in[13];
    const float* fc2_W2     = (const float*)d_in[14];
    const float* W_lin2_2   = (const float*)d_in[15];
    const int*   esrc       = (const int*)d_in[16];
    const int*   edst       = (const int*)d_in[17];
    float* out = (float*)d_out;
    float* wsf = (float*)d_ws;

    float*    x1     = wsf + OFF_X1;
    float*    ssc    = wsf + OFF_SS;
    float*    mid    = wsf + OFF_MID;    // 64N; later reused as mid2 (48N)
    float*    mid2   = wsf + OFF_MID;
    float*    h0     = wsf + OFF_H0;
    float*    hv     = wsf + OFF_HV;
    float*    s2     = wsf + OFF_S2;
    int*      cnt    = (int*)(wsf + OFF_CNT);
    int*      offs   = (int*)(wsf + OFF_OFFS);
    int*      part   = (int*)(wsf + OFF_PART);
    int*      slotl  = (int*)(wsf + OFF_SLOTL);
    int*      slot   = (int*)(wsf + OFF_SLOT);
    unsigned* ef     = (unsigned*)(wsf + OFF_EF);

    // adaptive ef capacity (rows) from actual workspace size
    size_t total_f = ws_size / 4;
    size_t avail = (total_f > OFF_EF) ? (total_f - OFF_EF) : 0;
    long long C1 = (long long)(avail / 32); if (C1 > NE) C1 = NE; if (C1 < 1) C1 = 1;  // 64 bf16 rows
    long long C2 = (long long)(avail / 24); if (C2 > NE) C2 = NE; if (C2 < 1) C2 = 1;  // 48 bf16 rows

    dim3 blk(256);
    int nodeGrid = (NN + 255) / 256;
    int edgeGrid = (NE + 255) / 256;
    int waveGrid = (NN + 3) / 4;

    hipMemsetAsync(cnt, 0, (size_t)NN * sizeof(int), stream);
    hipMemsetAsync(mid, 0, (size_t)NN * 64 * sizeof(float), stream);

    // CSR: rank -> scan -> slot
    rank_k<<<edgeGrid, blk, 0, stream>>>(edst, cnt, slotl);
    s1_partial<<<NSCAN, SCAN_B, 0, stream>>>(cnt, part);
    s2_scan<<<1, 1, 0, stream>>>(part);
    s3_offsets<<<NSCAN, SCAN_B, 0, stream>>>(cnt, part, offs);
    slot_k<<<edgeGrid, blk, 0, stream>>>(edst, slotl, offs, slot);

    // node pre
    k1_nodes<<<nodeGrid, blk, 0, stream>>>(node_input, node_attr, W_sc1, W_lin1_1, x1, ssc);

    // pass 1
    for (long long b = 0; b < NE; b += C1) {
        int len = (int)((NE - b < C1) ? (NE - b) : C1);
        e1_mfma<<<edgeGrid, blk, 0, stream>>>(ele, edge_attr, esrc, slot,
                                              fc1_W1, fc1_W2, x1,
                                              ef, (int)b, len);
        g1_gather<<<waveGrid, blk, 0, stream>>>(offs, cnt, ef, (int)b, len, mid);
    }

    // node mid
    k3_nodes<<<nodeGrid, blk, 0, stream>>>(node_attr, ssc, mid, W_l2s_1, W_l2v_1, W_sc2,
                                           W_lin1_2s, W_lin1_2v, h0, hv, s2);

    hipMemsetAsync(mid2, 0, (size_t)NN * 48 * sizeof(float), stream);

    // pass 2
    for (long long b = 0; b < NE; b += C2) {
        int len = (int)((NE - b < C2) ? (NE - b) : C2);
        e2_mfma<<<edgeGrid, blk, 0, stream>>>(ele, edge_attr, esrc, slot,
                                              fc2_W1, fc2_W2, h0, hv,
                                              ef, (int)b, len);
        g2_gather<<<waveGrid, blk, 0, stream>>>(offs, cnt, ef, (int)b, len, mid2);
    }

    // final
    k5_nodes<<<nodeGrid, blk, 0, stream>>>(node_attr, mid2, W_lin2_2, s2, out);
}